// Round 10
// baseline (382.346 us; speedup 1.0000x reference)
//
#include <hip/hip_runtime.h>
#include <math.h>

#define D_DIM   256
#define N_ROWS  16384
#define K_CODES 8192
#define NCHUNK  8          // 8 chunks of 1024 codes; chunk -> XCD

typedef __attribute__((ext_vector_type(8))) short s8v;           // 8 bf16 (A/B frag)
typedef __attribute__((ext_vector_type(4))) float f4v;           // 4 f32  (C/D frag)
typedef __attribute__((ext_vector_type(4))) unsigned short us4;  // 4 bf16 (8B write)
typedef unsigned long long u64;
typedef unsigned int u32;

// out layout: [0, 4194304) z_q_st | [4194304, 4210688) indices (as float) | [4210688] vq_loss
#define IDX_OFF  ((size_t)N_ROWS * D_DIM)
#define LOSS_OFF (IDX_OFF + N_ROWS)

// ws layout (27 MB used):
//   [0, 2MB)        u64 cand[N_ROWS][NCHUNK][2]
//   [2MB, +32KB)    float enorm[8192]
//   [+32KB, +16KB)  float partials[4096]
//   [3MB, 11MB)     bf16 zh_t  K-major: [d0b][lg][row][16B]  (d0b<8, lg<4)
//   [11MB, 19MB)    bf16 zl_t  same
//   [19MB, 23MB)    bf16 eh_t  [d0b][lg][code][16B]
//   [23MB, 27MB)    bf16 el_t  same
#define WS_ENORM_OFF    (2u * 1024u * 1024u)
#define WS_PARTIAL_OFF  (WS_ENORM_OFF + 32768u)
#define WS_ZH_OFF       (3u * 1024u * 1024u)
#define WS_ZL_OFF       (11u * 1024u * 1024u)
#define WS_EH_OFF       (19u * 1024u * 1024u)
#define WS_EL_OFF       (23u * 1024u * 1024u)

__device__ __forceinline__ unsigned short f2bf(float f) {   // fp32 -> bf16 RNE
    u32 u = __float_as_uint(f);
    return (unsigned short)((u + 0x7fffu + ((u >> 16) & 1u)) >> 16);
}
__device__ __forceinline__ float bf2f(unsigned short b) {
    return __uint_as_float(((u32)b) << 16);
}
__device__ __forceinline__ u32 f2ord(float f) {             // monotonic fp32 -> u32
    u32 u = __float_as_uint(f);
    return (u & 0x80000000u) ? ~u : (u | 0x80000000u);
}
__device__ __forceinline__ void gl2lds16(const void* g, void* l) {
    __builtin_amdgcn_global_load_lds(
        (const __attribute__((address_space(1))) unsigned int*)g,
        (__attribute__((address_space(3))) unsigned int*)l, 16, 0, 0);
}

// ---- pre-convert: z -> zh_t, zl_t (K-major tiling) ----
__global__ __launch_bounds__(256) void zconv_kernel(const float* __restrict__ z,
                                                    unsigned short* __restrict__ zh,
                                                    unsigned short* __restrict__ zl) {
    int q = blockIdx.x * 256 + threadIdx.x;        // float4 index, 0..1048575
    float4 v = reinterpret_cast<const float4*>(z)[q];
    us4 h, lo;
    h[0] = f2bf(v.x); lo[0] = f2bf(v.x - bf2f(h[0]));
    h[1] = f2bf(v.y); lo[1] = f2bf(v.y - bf2f(h[1]));
    h[2] = f2bf(v.z); lo[2] = f2bf(v.z - bf2f(h[2]));
    h[3] = f2bf(v.w); lo[3] = f2bf(v.w - bf2f(h[3]));
    int row = q >> 6;                               // 64 float4 per row
    int f   = q & 63;                               // d = f*4 .. f*4+3
    int d0b = f >> 3, lg = (f >> 1) & 3, half = f & 1;
    size_t off = ((size_t)(d0b * 4 + lg) * N_ROWS + row) * 16 + half * 8;
    *reinterpret_cast<us4*>((char*)zh + off) = h;
    *reinterpret_cast<us4*>((char*)zl + off) = lo;
}

// ---- pre-convert: emb -> eh_t, el_t (K-major tiling) ----
__global__ __launch_bounds__(256) void econv_kernel(const float* __restrict__ emb,
                                                    unsigned short* __restrict__ eh,
                                                    unsigned short* __restrict__ el) {
    int q = blockIdx.x * 256 + threadIdx.x;        // 0..524287
    float4 v = reinterpret_cast<const float4*>(emb)[q];
    us4 h, lo;
    h[0] = f2bf(v.x); lo[0] = f2bf(v.x - bf2f(h[0]));
    h[1] = f2bf(v.y); lo[1] = f2bf(v.y - bf2f(h[1]));
    h[2] = f2bf(v.z); lo[2] = f2bf(v.z - bf2f(h[2]));
    h[3] = f2bf(v.w); lo[3] = f2bf(v.w - bf2f(h[3]));
    int row = q >> 6;
    int f   = q & 63;
    int d0b = f >> 3, lg = (f >> 1) & 3, half = f & 1;
    size_t off = ((size_t)(d0b * 4 + lg) * K_CODES + row) * 16 + half * 8;
    *reinterpret_cast<us4*>((char*)eh + off) = h;
    *reinterpret_cast<us4*>((char*)el + off) = lo;
}

__global__ __launch_bounds__(256) void enorm_kernel(const float* __restrict__ emb,
                                                    float* __restrict__ enorm) {
    int row  = blockIdx.x * 4 + (threadIdx.x >> 6);
    int lane = threadIdx.x & 63;
    float4 v = reinterpret_cast<const float4*>(emb + (size_t)row * D_DIM)[lane];
    float s = v.x * v.x + v.y * v.y + v.z * v.z + v.w * v.w;
    #pragma unroll
    for (int off = 32; off >= 1; off >>= 1) s += __shfl_down(s, off);
    if (lane == 0) enorm[row] = s;
}

// ---------------- MFMA argmin: swapped operands, 64x64 wave tile ----------------
// Block: 128 codes x 128 rows per ct-step; 4 waves (wm,wn) 2x2, each 64x64.
// LDS 32KB: eh[lg][128][16B] | el | zh[lg][128][16B] | zl  (8KB each).
// All frag reads contiguous 256B per 16-lane group -> conflict-free.
__global__ __launch_bounds__(256, 3) void argmin_kernel(const unsigned short* __restrict__ zh,
                                                        const unsigned short* __restrict__ zl,
                                                        const unsigned short* __restrict__ eh,
                                                        const unsigned short* __restrict__ el,
                                                        const float* __restrict__ enorm,
                                                        u64* __restrict__ cand) {
    __shared__ __align__(16) unsigned char lds[32768];

    const int tid = threadIdx.x;
    const int wv  = tid >> 6;
    const int l   = tid & 63;
    const int lr  = l & 15;
    const int lg  = l >> 4;
    const int wm  = wv >> 1;                // row half: rows wm*64..+63
    const int wn  = wv & 1;                 // code half: codes wn*64..+63
    const int wg  = blockIdx.x;
    const int r0    = (wg >> 3) * 128;
    const int ch    = wg & 7;               // chunk == XCD
    const int cbase = ch * 1024;

    const char* zhp = (const char*)zh;
    const char* zlp = (const char*)zl;
    const char* ehp = (const char*)eh;
    const char* elp = (const char*)el;

    u64 t1[4], t2[4];                       // top-2 per owned row-tile j
    #pragma unroll
    for (int j = 0; j < 4; ++j) { t1[j] = ~0ULL; t2[j] = ~0ULL; }

    for (int ct = 0; ct < 8; ++ct) {
        const int cb = cbase + ct * 128;
        f4v acc[4][4];
        #pragma unroll
        for (int i = 0; i < 4; ++i)
            #pragma unroll
            for (int j = 0; j < 4; ++j)
                acc[i][j] = (f4v){0.f, 0.f, 0.f, 0.f};

        for (int d0b = 0; d0b < 8; ++d0b) {
            __syncthreads();                               // prev readers done
            // stage 2048 x 16B chunks: eh | el | zh | zl, K-major segments
            #pragma unroll
            for (int it = 0; it < 8; ++it) {
                int u   = it * 256 + tid;
                int v   = u & 511;
                int slg = v >> 7;
                int idx = v & 127;
                const char* sp;
                size_t soff;
                if (it < 2)      { sp = ehp; soff = ((size_t)(d0b * 4 + slg) * K_CODES + cb + idx) * 16; }
                else if (it < 4) { sp = elp; soff = ((size_t)(d0b * 4 + slg) * K_CODES + cb + idx) * 16; }
                else if (it < 6) { sp = zhp; soff = ((size_t)(d0b * 4 + slg) * N_ROWS + r0 + idx) * 16; }
                else             { sp = zlp; soff = ((size_t)(d0b * 4 + slg) * N_ROWS + r0 + idx) * 16; }
                gl2lds16(sp + soff, (char*)lds + u * 16);
            }
            __syncthreads();                               // tiles ready

            s8v zhf[4], zlf[4];
            #pragma unroll
            for (int j = 0; j < 4; ++j) {
                int row = wm * 64 + j * 16 + lr;
                zhf[j] = *reinterpret_cast<const s8v*>(lds + 16384 + lg * 2048 + row * 16);
                zlf[j] = *reinterpret_cast<const s8v*>(lds + 24576 + lg * 2048 + row * 16);
            }
            #pragma unroll
            for (int i = 0; i < 4; ++i) {
                int code = wn * 64 + i * 16 + lr;
                s8v ehf = *reinterpret_cast<const s8v*>(lds + lg * 2048 + code * 16);
                s8v elf = *reinterpret_cast<const s8v*>(lds + 8192 + lg * 2048 + code * 16);
                #pragma unroll
                for (int j = 0; j < 4; ++j) {
                    acc[i][j] = __builtin_amdgcn_mfma_f32_16x16x32_bf16(ehf, zhf[j], acc[i][j], 0, 0, 0);
                    acc[i][j] = __builtin_amdgcn_mfma_f32_16x16x32_bf16(elf, zhf[j], acc[i][j], 0, 0, 0);
                    acc[i][j] = __builtin_amdgcn_mfma_f32_16x16x32_bf16(ehf, zlf[j], acc[i][j], 0, 0, 0);
                }
            }
        }

        // epilogue: dist = enorm[c] - 2*dot; D row-quad = code, D col(lr) = z-row
        #pragma unroll
        for (int i = 0; i < 4; ++i)
            #pragma unroll
            for (int r = 0; r < 4; ++r) {
                int code = cb + wn * 64 + i * 16 + lg * 4 + r;
                float en = enorm[code];
                #pragma unroll
                for (int j = 0; j < 4; ++j) {
                    float dist = fmaf(-2.f, acc[i][j][r], en);
                    u64 key = ((u64)f2ord(dist) << 32) | (u32)code;
                    if (key < t1[j])      { t2[j] = t1[j]; t1[j] = key; }
                    else if (key < t2[j]) { t2[j] = key; }
                }
            }
    }

    // cross-lane (lg) top-2 merge: lanes sharing (j, lr) hold same z-row
    #pragma unroll
    for (int j = 0; j < 4; ++j) {
        u64 a1 = t1[j], a2 = t2[j];
        #pragma unroll
        for (int mk = 16; mk <= 32; mk <<= 1) {
            u64 o1 = __shfl_xor(a1, mk);
            u64 o2 = __shfl_xor(a2, mk);
            u64 n1 = a1 < o1 ? a1 : o1;
            u64 hi = a1 < o1 ? o1 : a1;
            u64 m2 = a2 < o2 ? a2 : o2;
            a1 = n1;
            a2 = hi < m2 ? hi : m2;
        }
        t1[j] = a1; t2[j] = a2;
    }

    // cross-wave (wn) merge via LDS, then write cand[row][ch][2]
    __syncthreads();
    u64* mbuf = (u64*)lds;                   // 2KB reuse
    if (wn == 1 && lg == 0) {
        #pragma unroll
        for (int j = 0; j < 4; ++j) {
            int s = ((wm * 4 + j) * 16 + lr) * 2;
            mbuf[s] = t1[j]; mbuf[s + 1] = t2[j];
        }
    }
    __syncthreads();
    if (wn == 0 && lg == 0) {
        #pragma unroll
        for (int j = 0; j < 4; ++j) {
            int s = ((wm * 4 + j) * 16 + lr) * 2;
            u64 b1 = mbuf[s], b2 = mbuf[s + 1];
            u64 n1 = t1[j] < b1 ? t1[j] : b1;
            u64 hi = t1[j] < b1 ? b1 : t1[j];
            u64 m2 = t2[j] < b2 ? t2[j] : b2;
            u64 n2 = hi < m2 ? hi : m2;
            int row = r0 + wm * 64 + j * 16 + lr;
            cand[((size_t)row * NCHUNK + ch) * 2]     = n1;
            cand[((size_t)row * NCHUNK + ch) * 2 + 1] = n2;
        }
    }
}

// ---------------- exact fp32 rescore of 16 candidates + outputs ----------------
__global__ __launch_bounds__(256) void rescore_kernel(const float* __restrict__ z,
                                                      const float* __restrict__ emb,
                                                      const float* __restrict__ enorm,
                                                      const u64* __restrict__ cand,
                                                      float* __restrict__ out,
                                                      float* __restrict__ partials) {
    int row  = blockIdx.x * 4 + (threadIdx.x >> 6);
    int lane = threadIdx.x & 63;
    float4 zv = reinterpret_cast<const float4*>(z)[(size_t)row * 64 + lane];

    u64 best = ~0ULL;
    for (int s = 0; s < 2 * NCHUNK; ++s) {
        u32 c = ((u32)cand[(size_t)row * (2 * NCHUNK) + s]) & (K_CODES - 1);
        float4 ev = reinterpret_cast<const float4*>(emb)[(size_t)c * 64 + lane];
        float p = zv.x * ev.x + zv.y * ev.y + zv.z * ev.z + zv.w * ev.w;
        #pragma unroll
        for (int mk = 1; mk < 64; mk <<= 1) p += __shfl_xor(p, mk);
        float dist = fmaf(-2.f, p, enorm[c]);
        u64 key = ((u64)f2ord(dist) << 32) | c;
        best = key < best ? key : best;
    }
    u32 idx = ((u32)best) & (K_CODES - 1);
    if (lane == 0) out[IDX_OFF + row] = (float)idx;

    float4 ev = reinterpret_cast<const float4*>(emb)[(size_t)idx * 64 + lane];
    float tx = ev.x - zv.x, ty = ev.y - zv.y, tz = ev.z - zv.z, tw = ev.w - zv.w;
    float4 o;
    o.x = zv.x + tx; o.y = zv.y + ty; o.z = zv.z + tz; o.w = zv.w + tw;  // straight-through
    reinterpret_cast<float4*>(out)[(size_t)row * 64 + lane] = o;

    float s = tx * tx + ty * ty + tz * tz + tw * tw;
    #pragma unroll
    for (int off = 32; off >= 1; off >>= 1) s += __shfl_down(s, off);

    __shared__ float wsum[4];
    if (lane == 0) wsum[threadIdx.x >> 6] = s;
    __syncthreads();
    if (threadIdx.x == 0)
        partials[blockIdx.x] = (wsum[0] + wsum[1]) + (wsum[2] + wsum[3]);
}

__global__ __launch_bounds__(256) void loss_kernel(const float* __restrict__ partials,
                                                   float* __restrict__ out) {
    __shared__ float sm[256];
    float s = 0.0f;
    for (int i = threadIdx.x; i < 4096; i += 256) s += partials[i];
    sm[threadIdx.x] = s;
    __syncthreads();
    #pragma unroll
    for (int st = 128; st >= 1; st >>= 1) {
        if (threadIdx.x < st) sm[threadIdx.x] += sm[threadIdx.x + st];
        __syncthreads();
    }
    if (threadIdx.x == 0)
        out[LOSS_OFF] = sm[0] * (0.25f / (float)(N_ROWS * D_DIM));
}

extern "C" void kernel_launch(void* const* d_in, const int* in_sizes, int n_in,
                              void* d_out, int out_size, void* d_ws, size_t ws_size,
                              hipStream_t stream) {
    const float* z   = (const float*)d_in[0];
    const float* emb = (const float*)d_in[1];
    float* out = (float*)d_out;

    u64*   cand     = (u64*)d_ws;
    float* enorm    = (float*)((char*)d_ws + WS_ENORM_OFF);
    float* partials = (float*)((char*)d_ws + WS_PARTIAL_OFF);
    unsigned short* zh = (unsigned short*)((char*)d_ws + WS_ZH_OFF);
    unsigned short* zl = (unsigned short*)((char*)d_ws + WS_ZL_OFF);
    unsigned short* eh = (unsigned short*)((char*)d_ws + WS_EH_OFF);
    unsigned short* el = (unsigned short*)((char*)d_ws + WS_EL_OFF);

    zconv_kernel<<<4096, 256, 0, stream>>>(z, zh, zl);
    econv_kernel<<<2048, 256, 0, stream>>>(emb, eh, el);
    enorm_kernel<<<K_CODES / 4, 256, 0, stream>>>(emb, enorm);
    argmin_kernel<<<1024, 256, 0, stream>>>(zh, zl, eh, el, enorm, cand);
    rescore_kernel<<<N_ROWS / 4, 256, 0, stream>>>(z, emb, enorm, cand, out, partials);
    loss_kernel<<<1, 256, 0, stream>>>(partials, out);
}

// Round 12
// 289.922 us; speedup vs baseline: 1.3188x; 1.3188x over previous
//
#include <hip/hip_runtime.h>
#include <math.h>

#define D_DIM   256
#define N_ROWS  16384
#define K_CODES 8192
#define NCHUNK  8          // 8 chunks of 1024 codes; chunk -> XCD

typedef __attribute__((ext_vector_type(8))) short s8v;           // 8 bf16 (A/B frag)
typedef __attribute__((ext_vector_type(4))) float f4v;           // 4 f32  (C/D frag)
typedef __attribute__((ext_vector_type(4))) unsigned short us4;  // 4 bf16 (8B write)
typedef unsigned long long u64;
typedef unsigned int u32;

// out layout: [0, 4194304) z_q_st | [4194304, 4210688) indices (as float) | [4210688] vq_loss
#define IDX_OFF  ((size_t)N_ROWS * D_DIM)
#define LOSS_OFF (IDX_OFF + N_ROWS)

// ws layout (27 MB used):
//   [0, 2MB)        u64 cand[N_ROWS][NCHUNK][2]
//   [2MB, +32KB)    float enorm[8192]
//   [+32KB, +16KB)  float partials[4096]
//   [3MB, 11MB)     bf16 zh_t  K-major: [d0b][lg][row][16B]  (d0b<8, lg<4)
//   [11MB, 19MB)    bf16 zl_t  same
//   [19MB, 23MB)    bf16 eh_t  [d0b][lg][code][16B]
//   [23MB, 27MB)    bf16 el_t  same
#define WS_ENORM_OFF    (2u * 1024u * 1024u)
#define WS_PARTIAL_OFF  (WS_ENORM_OFF + 32768u)
#define WS_ZH_OFF       (3u * 1024u * 1024u)
#define WS_ZL_OFF       (11u * 1024u * 1024u)
#define WS_EH_OFF       (19u * 1024u * 1024u)
#define WS_EL_OFF       (23u * 1024u * 1024u)

__device__ __forceinline__ unsigned short f2bf(float f) {   // fp32 -> bf16 RNE
    u32 u = __float_as_uint(f);
    return (unsigned short)((u + 0x7fffu + ((u >> 16) & 1u)) >> 16);
}
__device__ __forceinline__ float bf2f(unsigned short b) {
    return __uint_as_float(((u32)b) << 16);
}
__device__ __forceinline__ u32 f2ord(float f) {             // monotonic fp32 -> u32
    u32 u = __float_as_uint(f);
    return (u & 0x80000000u) ? ~u : (u | 0x80000000u);
}
__device__ __forceinline__ void gl2lds16(const void* g, void* l) {
    __builtin_amdgcn_global_load_lds(
        (const __attribute__((address_space(1))) unsigned int*)g,
        (__attribute__((address_space(3))) unsigned int*)l, 16, 0, 0);
}

// ---- pre-convert: z -> zh_t, zl_t (K-major tiling) ----
__global__ __launch_bounds__(256) void zconv_kernel(const float* __restrict__ z,
                                                    unsigned short* __restrict__ zh,
                                                    unsigned short* __restrict__ zl) {
    int q = blockIdx.x * 256 + threadIdx.x;        // float4 index, 0..1048575
    float4 v = reinterpret_cast<const float4*>(z)[q];
    us4 h, lo;
    h[0] = f2bf(v.x); lo[0] = f2bf(v.x - bf2f(h[0]));
    h[1] = f2bf(v.y); lo[1] = f2bf(v.y - bf2f(h[1]));
    h[2] = f2bf(v.z); lo[2] = f2bf(v.z - bf2f(h[2]));
    h[3] = f2bf(v.w); lo[3] = f2bf(v.w - bf2f(h[3]));
    int row = q >> 6;                               // 64 float4 per row
    int f   = q & 63;                               // d = f*4 .. f*4+3
    int d0b = f >> 3, lg = (f >> 1) & 3, half = f & 1;
    size_t off = ((size_t)(d0b * 4 + lg) * N_ROWS + row) * 16 + half * 8;
    *reinterpret_cast<us4*>((char*)zh + off) = h;
    *reinterpret_cast<us4*>((char*)zl + off) = lo;
}

// ---- pre-convert: emb -> eh_t, el_t (K-major tiling) ----
__global__ __launch_bounds__(256) void econv_kernel(const float* __restrict__ emb,
                                                    unsigned short* __restrict__ eh,
                                                    unsigned short* __restrict__ el) {
    int q = blockIdx.x * 256 + threadIdx.x;        // 0..524287
    float4 v = reinterpret_cast<const float4*>(emb)[q];
    us4 h, lo;
    h[0] = f2bf(v.x); lo[0] = f2bf(v.x - bf2f(h[0]));
    h[1] = f2bf(v.y); lo[1] = f2bf(v.y - bf2f(h[1]));
    h[2] = f2bf(v.z); lo[2] = f2bf(v.z - bf2f(h[2]));
    h[3] = f2bf(v.w); lo[3] = f2bf(v.w - bf2f(h[3]));
    int row = q >> 6;
    int f   = q & 63;
    int d0b = f >> 3, lg = (f >> 1) & 3, half = f & 1;
    size_t off = ((size_t)(d0b * 4 + lg) * K_CODES + row) * 16 + half * 8;
    *reinterpret_cast<us4*>((char*)eh + off) = h;
    *reinterpret_cast<us4*>((char*)el + off) = lo;
}

__global__ __launch_bounds__(256) void enorm_kernel(const float* __restrict__ emb,
                                                    float* __restrict__ enorm) {
    int row  = blockIdx.x * 4 + (threadIdx.x >> 6);
    int lane = threadIdx.x & 63;
    float4 v = reinterpret_cast<const float4*>(emb + (size_t)row * D_DIM)[lane];
    float s = v.x * v.x + v.y * v.y + v.z * v.z + v.w * v.w;
    #pragma unroll
    for (int off = 32; off >= 1; off >>= 1) s += __shfl_down(s, off);
    if (lane == 0) enorm[row] = s;
}

// ---------------- MFMA argmin: swapped operands, T3 2-phase pipeline ----------------
// Block: 128 codes x 128 rows per ct-step; 4 waves (wm,wn) 2x2, each 64x64.
// LDS 64KB = 2 x 32KB dbuf {eh|el|zh|zl 8KB each}, K-major frag reads conflict-free.
// Per step: STAGE(next buf) issued FIRST -> frag-reads+MFMA(cur) -> ONE barrier
// (implicit vmcnt(0) drains the prefetch, which had the MFMA phase to land).
__global__ __launch_bounds__(256, 3) void argmin_kernel(const unsigned short* __restrict__ zh,
                                                        const unsigned short* __restrict__ zl,
                                                        const unsigned short* __restrict__ eh,
                                                        const unsigned short* __restrict__ el,
                                                        const float* __restrict__ enorm,
                                                        u64* __restrict__ cand) {
    __shared__ __align__(16) unsigned char lds[65536];

    const int tid = threadIdx.x;
    const int wv  = tid >> 6;
    const int l   = tid & 63;
    const int lr  = l & 15;
    const int lg  = l >> 4;
    const int wm  = wv >> 1;                // row half: rows wm*64..+63
    const int wn  = wv & 1;                 // code half: codes wn*64..+63
    const int wg  = blockIdx.x;
    const int r0    = (wg >> 3) * 128;
    const int ch    = wg & 7;               // chunk == XCD
    const int cbase = ch * 1024;

    const char* zhp = (const char*)zh;
    const char* zlp = (const char*)zl;
    const char* ehp = (const char*)eh;
    const char* elp = (const char*)el;

    // stage step s (ct = s>>3, d0b = s&7) into buffer b
    auto stage = [&](int s, int b) {
        const int cb  = cbase + (s >> 3) * 128;
        const int d0b = s & 7;
        char* dst = (char*)lds + b * 32768;
        #pragma unroll
        for (int it = 0; it < 8; ++it) {
            int u   = it * 256 + tid;
            int v   = u & 511;
            int slg = v >> 7;
            int idx = v & 127;
            const char* sp;
            size_t soff;
            if (it < 2)      { sp = ehp; soff = ((size_t)(d0b * 4 + slg) * K_CODES + cb + idx) * 16; }
            else if (it < 4) { sp = elp; soff = ((size_t)(d0b * 4 + slg) * K_CODES + cb + idx) * 16; }
            else if (it < 6) { sp = zhp; soff = ((size_t)(d0b * 4 + slg) * N_ROWS + r0 + idx) * 16; }
            else             { sp = zlp; soff = ((size_t)(d0b * 4 + slg) * N_ROWS + r0 + idx) * 16; }
            gl2lds16(sp + soff, dst + u * 16);
        }
    };

    u64 t1[4], t2[4];                       // top-2 per owned row-tile j
    #pragma unroll
    for (int j = 0; j < 4; ++j) { t1[j] = ~0ULL; t2[j] = ~0ULL; }

    f4v acc[4][4];
    #pragma unroll
    for (int i = 0; i < 4; ++i)
        #pragma unroll
        for (int j = 0; j < 4; ++j)
            acc[i][j] = (f4v){0.f, 0.f, 0.f, 0.f};

    stage(0, 0);
    __syncthreads();                        // prologue: buf0 ready

    for (int s = 0; s < 64; ++s) {
        const int b = s & 1;
        if (s < 63) stage(s + 1, b ^ 1);    // prefetch next step into other buffer

        const char* base = (const char*)lds + b * 32768;
        s8v zhf[4], zlf[4];
        #pragma unroll
        for (int j = 0; j < 4; ++j) {
            int row = wm * 64 + j * 16 + lr;
            zhf[j] = *reinterpret_cast<const s8v*>(base + 16384 + lg * 2048 + row * 16);
            zlf[j] = *reinterpret_cast<const s8v*>(base + 24576 + lg * 2048 + row * 16);
        }
        #pragma unroll
        for (int i = 0; i < 4; ++i) {
            int code = wn * 64 + i * 16 + lr;
            s8v ehf = *reinterpret_cast<const s8v*>(base + lg * 2048 + code * 16);
            s8v elf = *reinterpret_cast<const s8v*>(base + 8192 + lg * 2048 + code * 16);
            #pragma unroll
            for (int j = 0; j < 4; ++j) {
                acc[i][j] = __builtin_amdgcn_mfma_f32_16x16x32_bf16(ehf, zhf[j], acc[i][j], 0, 0, 0);
                acc[i][j] = __builtin_amdgcn_mfma_f32_16x16x32_bf16(elf, zhf[j], acc[i][j], 0, 0, 0);
                acc[i][j] = __builtin_amdgcn_mfma_f32_16x16x32_bf16(ehf, zlf[j], acc[i][j], 0, 0, 0);
            }
        }

        if ((s & 7) == 7) {
            // epilogue for ct = s>>3: dist = enorm[c] - 2*dot; update top-2; reset acc
            const int cb = cbase + (s >> 3) * 128;
            #pragma unroll
            for (int i = 0; i < 4; ++i)
                #pragma unroll
                for (int r = 0; r < 4; ++r) {
                    int code = cb + wn * 64 + i * 16 + lg * 4 + r;
                    float en = enorm[code];
                    #pragma unroll
                    for (int j = 0; j < 4; ++j) {
                        float dist = fmaf(-2.f, acc[i][j][r], en);
                        u64 key = ((u64)f2ord(dist) << 32) | (u32)code;
                        if (key < t1[j])      { t2[j] = t1[j]; t1[j] = key; }
                        else if (key < t2[j]) { t2[j] = key; }
                    }
                }
            #pragma unroll
            for (int i = 0; i < 4; ++i)
                #pragma unroll
                for (int j = 0; j < 4; ++j)
                    acc[i][j] = (f4v){0.f, 0.f, 0.f, 0.f};
        }

        __syncthreads();                    // drains prefetch (vmcnt 0) + read fence
    }

    // cross-lane (lg) top-2 merge: lanes sharing (j, lr) hold same z-row
    #pragma unroll
    for (int j = 0; j < 4; ++j) {
        u64 a1 = t1[j], a2 = t2[j];
        #pragma unroll
        for (int mk = 16; mk <= 32; mk <<= 1) {
            u64 o1 = __shfl_xor(a1, mk);
            u64 o2 = __shfl_xor(a2, mk);
            u64 n1 = a1 < o1 ? a1 : o1;
            u64 hi = a1 < o1 ? o1 : a1;
            u64 m2 = a2 < o2 ? a2 : o2;
            a1 = n1;
            a2 = hi < m2 ? hi : m2;
        }
        t1[j] = a1; t2[j] = a2;
    }

    // cross-wave (wn) merge via LDS, then write cand[row][ch][2]
    __syncthreads();
    u64* mbuf = (u64*)lds;                   // 2KB reuse
    if (wn == 1 && lg == 0) {
        #pragma unroll
        for (int j = 0; j < 4; ++j) {
            int s = ((wm * 4 + j) * 16 + lr) * 2;
            mbuf[s] = t1[j]; mbuf[s + 1] = t2[j];
        }
    }
    __syncthreads();
    if (wn == 0 && lg == 0) {
        #pragma unroll
        for (int j = 0; j < 4; ++j) {
            int s = ((wm * 4 + j) * 16 + lr) * 2;
            u64 b1 = mbuf[s], b2 = mbuf[s + 1];
            u64 n1 = t1[j] < b1 ? t1[j] : b1;
            u64 hi = t1[j] < b1 ? b1 : t1[j];
            u64 m2 = t2[j] < b2 ? t2[j] : b2;
            u64 n2 = hi < m2 ? hi : m2;
            int row = r0 + wm * 64 + j * 16 + lr;
            cand[((size_t)row * NCHUNK + ch) * 2]     = n1;
            cand[((size_t)row * NCHUNK + ch) * 2 + 1] = n2;
        }
    }
}

// ---------------- exact fp32 rescore of 16 candidates + outputs ----------------
__global__ __launch_bounds__(256) void rescore_kernel(const float* __restrict__ z,
                                                      const float* __restrict__ emb,
                                                      const float* __restrict__ enorm,
                                                      const u64* __restrict__ cand,
                                                      float* __restrict__ out,
                                                      float* __restrict__ partials) {
    int row  = blockIdx.x * 4 + (threadIdx.x >> 6);
    int lane = threadIdx.x & 63;
    float4 zv = reinterpret_cast<const float4*>(z)[(size_t)row * 64 + lane];

    u64 best = ~0ULL;
    for (int s = 0; s < 2 * NCHUNK; ++s) {
        u32 c = ((u32)cand[(size_t)row * (2 * NCHUNK) + s]) & (K_CODES - 1);
        float4 ev = reinterpret_cast<const float4*>(emb)[(size_t)c * 64 + lane];
        float p = zv.x * ev.x + zv.y * ev.y + zv.z * ev.z + zv.w * ev.w;
        #pragma unroll
        for (int mk = 1; mk < 64; mk <<= 1) p += __shfl_xor(p, mk);
        float dist = fmaf(-2.f, p, enorm[c]);
        u64 key = ((u64)f2ord(dist) << 32) | c;
        best = key < best ? key : best;
    }
    u32 idx = ((u32)best) & (K_CODES - 1);
    if (lane == 0) out[IDX_OFF + row] = (float)idx;

    float4 ev = reinterpret_cast<const float4*>(emb)[(size_t)idx * 64 + lane];
    float tx = ev.x - zv.x, ty = ev.y - zv.y, tz = ev.z - zv.z, tw = ev.w - zv.w;
    float4 o;
    o.x = zv.x + tx; o.y = zv.y + ty; o.z = zv.z + tz; o.w = zv.w + tw;  // straight-through
    reinterpret_cast<float4*>(out)[(size_t)row * 64 + lane] = o;

    float s = tx * tx + ty * ty + tz * tz + tw * tw;
    #pragma unroll
    for (int off = 32; off >= 1; off >>= 1) s += __shfl_down(s, off);

    __shared__ float wsum[4];
    if (lane == 0) wsum[threadIdx.x >> 6] = s;
    __syncthreads();
    if (threadIdx.x == 0)
        partials[blockIdx.x] = (wsum[0] + wsum[1]) + (wsum[2] + wsum[3]);
}

__global__ __launch_bounds__(256) void loss_kernel(const float* __restrict__ partials,
                                                   float* __restrict__ out) {
    __shared__ float sm[256];
    float s = 0.0f;
    for (int i = threadIdx.x; i < 4096; i += 256) s += partials[i];
    sm[threadIdx.x] = s;
    __syncthreads();
    #pragma unroll
    for (int st = 128; st >= 1; st >>= 1) {
        if (threadIdx.x < st) sm[threadIdx.x] += sm[threadIdx.x + st];
        __syncthreads();
    }
    if (threadIdx.x == 0)
        out[LOSS_OFF] = sm[0] * (0.25f / (float)(N_ROWS * D_DIM));
}

extern "C" void kernel_launch(void* const* d_in, const int* in_sizes, int n_in,
                              void* d_out, int out_size, void* d_ws, size_t ws_size,
                              hipStream_t stream) {
    const float* z   = (const float*)d_in[0];
    const float* emb = (const float*)d_in[1];
    float* out = (float*)d_out;

    u64*   cand     = (u64*)d_ws;
    float* enorm    = (float*)((char*)d_ws + WS_ENORM_OFF);
    float* partials = (float*)((char*)d_ws + WS_PARTIAL_OFF);
    unsigned short* zh = (unsigned short*)((char*)d_ws + WS_ZH_OFF);
    unsigned short* zl = (unsigned short*)((char*)d_ws + WS_ZL_OFF);
    unsigned short* eh = (unsigned short*)((char*)d_ws + WS_EH_OFF);
    unsigned short* el = (unsigned short*)((char*)d_ws + WS_EL_OFF);

    zconv_kernel<<<4096, 256, 0, stream>>>(z, zh, zl);
    econv_kernel<<<2048, 256, 0, stream>>>(emb, eh, el);
    enorm_kernel<<<K_CODES / 4, 256, 0, stream>>>(emb, enorm);
    argmin_kernel<<<1024, 256, 0, stream>>>(zh, zl, eh, el, enorm, cand);
    rescore_kernel<<<N_ROWS / 4, 256, 0, stream>>>(z, emb, enorm, cand, out, partials);
    loss_kernel<<<1, 256, 0, stream>>>(partials, out);
}

// Round 13
// 286.678 us; speedup vs baseline: 1.3337x; 1.0113x over previous
//
#include <hip/hip_runtime.h>
#include <math.h>

#define D_DIM   256
#define N_ROWS  16384
#define K_CODES 8192
#define NCHUNK  8          // 8 chunks of 1024 codes; chunk -> XCD

typedef __attribute__((ext_vector_type(8))) short s8v;           // 8 bf16 (A/B frag)
typedef __attribute__((ext_vector_type(4))) float f4v;           // 4 f32  (C/D frag)
typedef __attribute__((ext_vector_type(4))) unsigned short us4;  // 4 bf16 (8B write)
typedef unsigned long long u64;
typedef unsigned int u32;

// out layout: [0, 4194304) z_q_st | [4194304, 4210688) indices (as float) | [4210688] vq_loss
#define IDX_OFF  ((size_t)N_ROWS * D_DIM)
#define LOSS_OFF (IDX_OFF + N_ROWS)

// ws layout (27 MB used):
//   [0, 2MB)        u64 cand[N_ROWS][NCHUNK][2]
//   [2MB, +32KB)    float enorm[8192]
//   [+32KB, +16KB)  float partials[4096]
//   [3MB, 11MB)     bf16 zh_t  K-major: [d0b][lg][row][16B]  (d0b<8, lg<4)
//   [11MB, 19MB)    bf16 zl_t  same
//   [19MB, 23MB)    bf16 eh_t  [d0b][lg][code][16B]
//   [23MB, 27MB)    bf16 el_t  same
#define WS_ENORM_OFF    (2u * 1024u * 1024u)
#define WS_PARTIAL_OFF  (WS_ENORM_OFF + 32768u)
#define WS_ZH_OFF       (3u * 1024u * 1024u)
#define WS_ZL_OFF       (11u * 1024u * 1024u)
#define WS_EH_OFF       (19u * 1024u * 1024u)
#define WS_EL_OFF       (23u * 1024u * 1024u)

__device__ __forceinline__ unsigned short f2bf(float f) {   // fp32 -> bf16 RNE
    u32 u = __float_as_uint(f);
    return (unsigned short)((u + 0x7fffu + ((u >> 16) & 1u)) >> 16);
}
__device__ __forceinline__ float bf2f(unsigned short b) {
    return __uint_as_float(((u32)b) << 16);
}
__device__ __forceinline__ u32 f2ord(float f) {             // monotonic fp32 -> u32
    u32 u = __float_as_uint(f);
    return (u & 0x80000000u) ? ~u : (u | 0x80000000u);
}
__device__ __forceinline__ void gl2lds16(const void* g, void* l) {
    __builtin_amdgcn_global_load_lds(
        (const __attribute__((address_space(1))) unsigned int*)g,
        (__attribute__((address_space(3))) unsigned int*)l, 16, 0, 0);
}

// ---- pre-convert: z -> zh_t, zl_t (K-major tiling) ----
__global__ __launch_bounds__(256) void zconv_kernel(const float* __restrict__ z,
                                                    unsigned short* __restrict__ zh,
                                                    unsigned short* __restrict__ zl) {
    int q = blockIdx.x * 256 + threadIdx.x;        // float4 index, 0..1048575
    float4 v = reinterpret_cast<const float4*>(z)[q];
    us4 h, lo;
    h[0] = f2bf(v.x); lo[0] = f2bf(v.x - bf2f(h[0]));
    h[1] = f2bf(v.y); lo[1] = f2bf(v.y - bf2f(h[1]));
    h[2] = f2bf(v.z); lo[2] = f2bf(v.z - bf2f(h[2]));
    h[3] = f2bf(v.w); lo[3] = f2bf(v.w - bf2f(h[3]));
    int row = q >> 6;                               // 64 float4 per row
    int f   = q & 63;                               // d = f*4 .. f*4+3
    int d0b = f >> 3, lg = (f >> 1) & 3, half = f & 1;
    size_t off = ((size_t)(d0b * 4 + lg) * N_ROWS + row) * 16 + half * 8;
    *reinterpret_cast<us4*>((char*)zh + off) = h;
    *reinterpret_cast<us4*>((char*)zl + off) = lo;
}

// ---- pre-convert: emb -> eh_t, el_t (K-major tiling) ----
__global__ __launch_bounds__(256) void econv_kernel(const float* __restrict__ emb,
                                                    unsigned short* __restrict__ eh,
                                                    unsigned short* __restrict__ el) {
    int q = blockIdx.x * 256 + threadIdx.x;        // 0..524287
    float4 v = reinterpret_cast<const float4*>(emb)[q];
    us4 h, lo;
    h[0] = f2bf(v.x); lo[0] = f2bf(v.x - bf2f(h[0]));
    h[1] = f2bf(v.y); lo[1] = f2bf(v.y - bf2f(h[1]));
    h[2] = f2bf(v.z); lo[2] = f2bf(v.z - bf2f(h[2]));
    h[3] = f2bf(v.w); lo[3] = f2bf(v.w - bf2f(h[3]));
    int row = q >> 6;
    int f   = q & 63;
    int d0b = f >> 3, lg = (f >> 1) & 3, half = f & 1;
    size_t off = ((size_t)(d0b * 4 + lg) * K_CODES + row) * 16 + half * 8;
    *reinterpret_cast<us4*>((char*)eh + off) = h;
    *reinterpret_cast<us4*>((char*)el + off) = lo;
}

__global__ __launch_bounds__(256) void enorm_kernel(const float* __restrict__ emb,
                                                    float* __restrict__ enorm) {
    int row  = blockIdx.x * 4 + (threadIdx.x >> 6);
    int lane = threadIdx.x & 63;
    float4 v = reinterpret_cast<const float4*>(emb + (size_t)row * D_DIM)[lane];
    float s = v.x * v.x + v.y * v.y + v.z * v.z + v.w * v.w;
    #pragma unroll
    for (int off = 32; off >= 1; off >>= 1) s += __shfl_down(s, off);
    if (lane == 0) enorm[row] = s;
}

// ---------------- MFMA argmin: T4 counted-vmcnt 2-deep pipeline ----------------
// Block: 128 codes x 128 rows per ct-step; 4 waves (wm,wn) 2x2, each 64x64.
// LDS: 2 x 32KB dbuf {eh|el|zh|zl 8KB each} + 4KB enorm slice (lgkm-side reads).
// Per step s: vmcnt(8) [stage(s) landed; stage(s+1) in flight] -> barrier ->
// ds-read frags -> lgkmcnt(0)+sched_barrier -> barrier -> stage(s+2) ->
// setprio(1) MFMA setprio(0). Never vmcnt(0) in-loop (only s=63 tail).
__global__ __launch_bounds__(256, 3) void argmin_kernel(const unsigned short* __restrict__ zh,
                                                        const unsigned short* __restrict__ zl,
                                                        const unsigned short* __restrict__ eh,
                                                        const unsigned short* __restrict__ el,
                                                        const float* __restrict__ enorm,
                                                        u64* __restrict__ cand) {
    __shared__ __align__(16) unsigned char lds[69632];   // 64KB dbuf + 4KB enorm

    const int tid = threadIdx.x;
    const int wv  = tid >> 6;
    const int l   = tid & 63;
    const int lr  = l & 15;
    const int lg  = l >> 4;
    const int wm  = wv >> 1;                // row half: rows wm*64..+63
    const int wn  = wv & 1;                 // code half: codes wn*64..+63
    const int wg  = blockIdx.x;
    const int r0    = (wg >> 3) * 128;
    const int ch    = wg & 7;               // chunk == XCD
    const int cbase = ch * 1024;

    const char* zhp = (const char*)zh;
    const char* zlp = (const char*)zl;
    const char* ehp = (const char*)eh;
    const char* elp = (const char*)el;

    // stage step s (ct = s>>3, d0b = s&7) into buffer b
    auto stage = [&](int s, int b) {
        const int cb  = cbase + (s >> 3) * 128;
        const int d0b = s & 7;
        char* dst = (char*)lds + b * 32768;
        #pragma unroll
        for (int it = 0; it < 8; ++it) {
            int u   = it * 256 + tid;
            int v   = u & 511;
            int slg = v >> 7;
            int idx = v & 127;
            const char* sp;
            size_t soff;
            if (it < 2)      { sp = ehp; soff = ((size_t)(d0b * 4 + slg) * K_CODES + cb + idx) * 16; }
            else if (it < 4) { sp = elp; soff = ((size_t)(d0b * 4 + slg) * K_CODES + cb + idx) * 16; }
            else if (it < 6) { sp = zhp; soff = ((size_t)(d0b * 4 + slg) * N_ROWS + r0 + idx) * 16; }
            else             { sp = zlp; soff = ((size_t)(d0b * 4 + slg) * N_ROWS + r0 + idx) * 16; }
            gl2lds16(sp + soff, dst + u * 16);
        }
    };

    u64 t1[4], t2[4];                       // top-2 per owned row-tile j
    #pragma unroll
    for (int j = 0; j < 4; ++j) { t1[j] = ~0ULL; t2[j] = ~0ULL; }

    f4v acc[4][4];
    #pragma unroll
    for (int i = 0; i < 4; ++i)
        #pragma unroll
        for (int j = 0; j < 4; ++j)
            acc[i][j] = (f4v){0.f, 0.f, 0.f, 0.f};

    // prologue: enorm slice (4KB, oldest in vmcnt queue) + steps 0,1
    gl2lds16((const char*)enorm + (size_t)cbase * 4 + tid * 16,
             (char*)lds + 65536 + tid * 16);
    stage(0, 0);
    stage(1, 1);

    for (int s = 0; s < 64; ++s) {
        const int b = s & 1;
        // stage(s) complete; stage(s+1)'s 8 loads may remain in flight
        if (s < 63) asm volatile("s_waitcnt vmcnt(8)" ::: "memory");
        else        asm volatile("s_waitcnt vmcnt(0)" ::: "memory");
        __builtin_amdgcn_s_barrier();       // all waves see buf b filled

        const char* base = (const char*)lds + b * 32768;
        s8v zhf[4], zlf[4];
        #pragma unroll
        for (int j = 0; j < 4; ++j) {
            int row = wm * 64 + j * 16 + lr;
            zhf[j] = *reinterpret_cast<const s8v*>(base + 16384 + lg * 2048 + row * 16);
            zlf[j] = *reinterpret_cast<const s8v*>(base + 24576 + lg * 2048 + row * 16);
        }
        s8v ehf[4], elf[4];
        #pragma unroll
        for (int i = 0; i < 4; ++i) {
            int code = wn * 64 + i * 16 + lr;
            ehf[i] = *reinterpret_cast<const s8v*>(base + lg * 2048 + code * 16);
            elf[i] = *reinterpret_cast<const s8v*>(base + 8192 + lg * 2048 + code * 16);
        }
        asm volatile("s_waitcnt lgkmcnt(0)" ::: "memory");
        __builtin_amdgcn_sched_barrier(0);  // rule #18: pin reads before barrier
        __builtin_amdgcn_s_barrier();       // all waves done reading buf b

        if (s + 2 < 64) stage(s + 2, b);    // overwrite buf b for step s+2

        __builtin_amdgcn_s_setprio(1);
        #pragma unroll
        for (int i = 0; i < 4; ++i)
            #pragma unroll
            for (int j = 0; j < 4; ++j) {
                acc[i][j] = __builtin_amdgcn_mfma_f32_16x16x32_bf16(ehf[i], zhf[j], acc[i][j], 0, 0, 0);
                acc[i][j] = __builtin_amdgcn_mfma_f32_16x16x32_bf16(elf[i], zhf[j], acc[i][j], 0, 0, 0);
                acc[i][j] = __builtin_amdgcn_mfma_f32_16x16x32_bf16(ehf[i], zlf[j], acc[i][j], 0, 0, 0);
            }
        __builtin_amdgcn_s_setprio(0);

        if ((s & 7) == 7) {
            // epilogue for ct = s>>3: dist = enorm[c] - 2*dot (enorm from LDS)
            const int cbl = (s >> 3) * 128;
            #pragma unroll
            for (int i = 0; i < 4; ++i)
                #pragma unroll
                for (int r = 0; r < 4; ++r) {
                    int cloc = cbl + wn * 64 + i * 16 + lg * 4 + r;
                    float en = *reinterpret_cast<const float*>(lds + 65536 + cloc * 4);
                    int code = cbase + cloc;
                    #pragma unroll
                    for (int j = 0; j < 4; ++j) {
                        float dist = fmaf(-2.f, acc[i][j][r], en);
                        u64 key = ((u64)f2ord(dist) << 32) | (u32)code;
                        if (key < t1[j])      { t2[j] = t1[j]; t1[j] = key; }
                        else if (key < t2[j]) { t2[j] = key; }
                    }
                }
            #pragma unroll
            for (int i = 0; i < 4; ++i)
                #pragma unroll
                for (int j = 0; j < 4; ++j)
                    acc[i][j] = (f4v){0.f, 0.f, 0.f, 0.f};
        }
    }

    // cross-lane (lg) top-2 merge: lanes sharing (j, lr) hold same z-row
    #pragma unroll
    for (int j = 0; j < 4; ++j) {
        u64 a1 = t1[j], a2 = t2[j];
        #pragma unroll
        for (int mk = 16; mk <= 32; mk <<= 1) {
            u64 o1 = __shfl_xor(a1, mk);
            u64 o2 = __shfl_xor(a2, mk);
            u64 n1 = a1 < o1 ? a1 : o1;
            u64 hi = a1 < o1 ? o1 : a1;
            u64 m2 = a2 < o2 ? a2 : o2;
            a1 = n1;
            a2 = hi < m2 ? hi : m2;
        }
        t1[j] = a1; t2[j] = a2;
    }

    // cross-wave (wn) merge via LDS, then write cand[row][ch][2]
    __syncthreads();
    u64* mbuf = (u64*)lds;                   // 2KB reuse
    if (wn == 1 && lg == 0) {
        #pragma unroll
        for (int j = 0; j < 4; ++j) {
            int s = ((wm * 4 + j) * 16 + lr) * 2;
            mbuf[s] = t1[j]; mbuf[s + 1] = t2[j];
        }
    }
    __syncthreads();
    if (wn == 0 && lg == 0) {
        #pragma unroll
        for (int j = 0; j < 4; ++j) {
            int s = ((wm * 4 + j) * 16 + lr) * 2;
            u64 b1 = mbuf[s], b2 = mbuf[s + 1];
            u64 n1 = t1[j] < b1 ? t1[j] : b1;
            u64 hi = t1[j] < b1 ? b1 : t1[j];
            u64 m2 = t2[j] < b2 ? t2[j] : b2;
            u64 n2 = hi < m2 ? hi : m2;
            int row = r0 + wm * 64 + j * 16 + lr;
            cand[((size_t)row * NCHUNK + ch) * 2]     = n1;
            cand[((size_t)row * NCHUNK + ch) * 2 + 1] = n2;
        }
    }
}

// ---------------- exact fp32 rescore of 16 candidates + outputs ----------------
__global__ __launch_bounds__(256) void rescore_kernel(const float* __restrict__ z,
                                                      const float* __restrict__ emb,
                                                      const float* __restrict__ enorm,
                                                      const u64* __restrict__ cand,
                                                      float* __restrict__ out,
                                                      float* __restrict__ partials) {
    int row  = blockIdx.x * 4 + (threadIdx.x >> 6);
    int lane = threadIdx.x & 63;
    float4 zv = reinterpret_cast<const float4*>(z)[(size_t)row * 64 + lane];

    u64 best = ~0ULL;
    for (int s = 0; s < 2 * NCHUNK; ++s) {
        u32 c = ((u32)cand[(size_t)row * (2 * NCHUNK) + s]) & (K_CODES - 1);
        float4 ev = reinterpret_cast<const float4*>(emb)[(size_t)c * 64 + lane];
        float p = zv.x * ev.x + zv.y * ev.y + zv.z * ev.z + zv.w * ev.w;
        #pragma unroll
        for (int mk = 1; mk < 64; mk <<= 1) p += __shfl_xor(p, mk);
        float dist = fmaf(-2.f, p, enorm[c]);
        u64 key = ((u64)f2ord(dist) << 32) | c;
        best = key < best ? key : best;
    }
    u32 idx = ((u32)best) & (K_CODES - 1);
    if (lane == 0) out[IDX_OFF + row] = (float)idx;

    float4 ev = reinterpret_cast<const float4*>(emb)[(size_t)idx * 64 + lane];
    float tx = ev.x - zv.x, ty = ev.y - zv.y, tz = ev.z - zv.z, tw = ev.w - zv.w;
    float4 o;
    o.x = zv.x + tx; o.y = zv.y + ty; o.z = zv.z + tz; o.w = zv.w + tw;  // straight-through
    reinterpret_cast<float4*>(out)[(size_t)row * 64 + lane] = o;

    float s = tx * tx + ty * ty + tz * tz + tw * tw;
    #pragma unroll
    for (int off = 32; off >= 1; off >>= 1) s += __shfl_down(s, off);

    __shared__ float wsum[4];
    if (lane == 0) wsum[threadIdx.x >> 6] = s;
    __syncthreads();
    if (threadIdx.x == 0)
        partials[blockIdx.x] = (wsum[0] + wsum[1]) + (wsum[2] + wsum[3]);
}

__global__ __launch_bounds__(256) void loss_kernel(const float* __restrict__ partials,
                                                   float* __restrict__ out) {
    __shared__ float sm[256];
    float s = 0.0f;
    for (int i = threadIdx.x; i < 4096; i += 256) s += partials[i];
    sm[threadIdx.x] = s;
    __syncthreads();
    #pragma unroll
    for (int st = 128; st >= 1; st >>= 1) {
        if (threadIdx.x < st) sm[threadIdx.x] += sm[threadIdx.x + st];
        __syncthreads();
    }
    if (threadIdx.x == 0)
        out[LOSS_OFF] = sm[0] * (0.25f / (float)(N_ROWS * D_DIM));
}

extern "C" void kernel_launch(void* const* d_in, const int* in_sizes, int n_in,
                              void* d_out, int out_size, void* d_ws, size_t ws_size,
                              hipStream_t stream) {
    const float* z   = (const float*)d_in[0];
    const float* emb = (const float*)d_in[1];
    float* out = (float*)d_out;

    u64*   cand     = (u64*)d_ws;
    float* enorm    = (float*)((char*)d_ws + WS_ENORM_OFF);
    float* partials = (float*)((char*)d_ws + WS_PARTIAL_OFF);
    unsigned short* zh = (unsigned short*)((char*)d_ws + WS_ZH_OFF);
    unsigned short* zl = (unsigned short*)((char*)d_ws + WS_ZL_OFF);
    unsigned short* eh = (unsigned short*)((char*)d_ws + WS_EH_OFF);
    unsigned short* el = (unsigned short*)((char*)d_ws + WS_EL_OFF);

    zconv_kernel<<<4096, 256, 0, stream>>>(z, zh, zl);
    econv_kernel<<<2048, 256, 0, stream>>>(emb, eh, el);
    enorm_kernel<<<K_CODES / 4, 256, 0, stream>>>(emb, enorm);
    argmin_kernel<<<1024, 256, 0, stream>>>(zh, zl, eh, el, enorm, cand);
    rescore_kernel<<<N_ROWS / 4, 256, 0, stream>>>(z, emb, enorm, cand, out, partials);
    loss_kernel<<<1, 256, 0, stream>>>(partials, out);
}

// Round 14
// 271.618 us; speedup vs baseline: 1.4077x; 1.0554x over previous
//
#include <hip/hip_runtime.h>
#include <math.h>

#define D_DIM   256
#define N_ROWS  16384
#define K_CODES 8192
#define NCHUNK  8          // 8 chunks of 1024 codes; chunk -> XCD

typedef __attribute__((ext_vector_type(8))) short s8v;           // 8 bf16 (A/B frag)
typedef __attribute__((ext_vector_type(4))) float f4v;           // 4 f32  (C/D frag)
typedef __attribute__((ext_vector_type(4))) unsigned short us4;  // 4 bf16 (8B write)
typedef unsigned long long u64;
typedef unsigned int u32;

// out layout: [0, 4194304) z_q_st | [4194304, 4210688) indices (as float) | [4210688] vq_loss
#define IDX_OFF  ((size_t)N_ROWS * D_DIM)
#define LOSS_OFF (IDX_OFF + N_ROWS)

// ws layout (27 MB used):
//   [0, 2MB)        u64 cand[N_ROWS][NCHUNK][2]
//   [2MB, +32KB)    float enorm[8192]
//   [+32KB, +16KB)  float partials[4096]
//   [3MB, 11MB)     bf16 zh_t  K-major: [d0b][lg][row][16B]  (d0b<8, lg<4)
//   [11MB, 19MB)    bf16 zl_t  same
//   [19MB, 23MB)    bf16 eh_t  [d0b][lg][code][16B]
//   [23MB, 27MB)    bf16 el_t  same
#define WS_ENORM_OFF    (2u * 1024u * 1024u)
#define WS_PARTIAL_OFF  (WS_ENORM_OFF + 32768u)
#define WS_ZH_OFF       (3u * 1024u * 1024u)
#define WS_ZL_OFF       (11u * 1024u * 1024u)
#define WS_EH_OFF       (19u * 1024u * 1024u)
#define WS_EL_OFF       (23u * 1024u * 1024u)

__device__ __forceinline__ unsigned short f2bf(float f) {   // fp32 -> bf16 RNE
    u32 u = __float_as_uint(f);
    return (unsigned short)((u + 0x7fffu + ((u >> 16) & 1u)) >> 16);
}
__device__ __forceinline__ float bf2f(unsigned short b) {
    return __uint_as_float(((u32)b) << 16);
}
__device__ __forceinline__ u32 f2ord(float f) {             // monotonic fp32 -> u32
    u32 u = __float_as_uint(f);
    return (u & 0x80000000u) ? ~u : (u | 0x80000000u);
}
__device__ __forceinline__ void gl2lds16(const void* g, void* l) {
    __builtin_amdgcn_global_load_lds(
        (const __attribute__((address_space(1))) unsigned int*)g,
        (__attribute__((address_space(3))) unsigned int*)l, 16, 0, 0);
}

// ---- pre-convert: z -> zh_t, zl_t (K-major tiling) ----
__global__ __launch_bounds__(256) void zconv_kernel(const float* __restrict__ z,
                                                    unsigned short* __restrict__ zh,
                                                    unsigned short* __restrict__ zl) {
    int q = blockIdx.x * 256 + threadIdx.x;        // float4 index, 0..1048575
    float4 v = reinterpret_cast<const float4*>(z)[q];
    us4 h, lo;
    h[0] = f2bf(v.x); lo[0] = f2bf(v.x - bf2f(h[0]));
    h[1] = f2bf(v.y); lo[1] = f2bf(v.y - bf2f(h[1]));
    h[2] = f2bf(v.z); lo[2] = f2bf(v.z - bf2f(h[2]));
    h[3] = f2bf(v.w); lo[3] = f2bf(v.w - bf2f(h[3]));
    int row = q >> 6;                               // 64 float4 per row
    int f   = q & 63;                               // d = f*4 .. f*4+3
    int d0b = f >> 3, lg = (f >> 1) & 3, half = f & 1;
    size_t off = ((size_t)(d0b * 4 + lg) * N_ROWS + row) * 16 + half * 8;
    *reinterpret_cast<us4*>((char*)zh + off) = h;
    *reinterpret_cast<us4*>((char*)zl + off) = lo;
}

// ---- pre-convert: emb -> eh_t, el_t (K-major tiling) + enorm (fused) ----
__global__ __launch_bounds__(256) void econv_kernel(const float* __restrict__ emb,
                                                    unsigned short* __restrict__ eh,
                                                    unsigned short* __restrict__ el,
                                                    float* __restrict__ enorm) {
    int q = blockIdx.x * 256 + threadIdx.x;        // 0..524287
    float4 v = reinterpret_cast<const float4*>(emb)[q];

    // one wave == one codebook row (64 lanes x 4 floats): fused enorm
    float s = v.x * v.x + v.y * v.y + v.z * v.z + v.w * v.w;
    #pragma unroll
    for (int off = 32; off >= 1; off >>= 1) s += __shfl_down(s, off);

    us4 h, lo;
    h[0] = f2bf(v.x); lo[0] = f2bf(v.x - bf2f(h[0]));
    h[1] = f2bf(v.y); lo[1] = f2bf(v.y - bf2f(h[1]));
    h[2] = f2bf(v.z); lo[2] = f2bf(v.z - bf2f(h[2]));
    h[3] = f2bf(v.w); lo[3] = f2bf(v.w - bf2f(h[3]));
    int row = q >> 6;
    int f   = q & 63;
    if (f == 0) enorm[row] = s;
    int d0b = f >> 3, lg = (f >> 1) & 3, half = f & 1;
    size_t off = ((size_t)(d0b * 4 + lg) * K_CODES + row) * 16 + half * 8;
    *reinterpret_cast<us4*>((char*)eh + off) = h;
    *reinterpret_cast<us4*>((char*)el + off) = lo;
}

// ---------------- MFMA argmin: swapped operands, T3 2-phase pipeline ----------------
// Round-12 verified sync structure (stage-first -> frag+MFMA -> ONE barrier/step).
// This round: VALU trim only — strength-reduced stage addressing, enorm in LDS
// (lgkm-side, no vmcnt pollution), fp32 tournament top-2 epilogue.
__global__ __launch_bounds__(256, 3) void argmin_kernel(const unsigned short* __restrict__ zh,
                                                        const unsigned short* __restrict__ zl,
                                                        const unsigned short* __restrict__ eh,
                                                        const unsigned short* __restrict__ el,
                                                        const float* __restrict__ enorm,
                                                        u64* __restrict__ cand) {
    __shared__ __align__(16) unsigned char lds[69632];   // 64KB dbuf + 4KB enorm

    const int tid = threadIdx.x;
    const int wv  = tid >> 6;
    const int l   = tid & 63;
    const int lr  = l & 15;
    const int lg  = l >> 4;
    const int wm  = wv >> 1;                // row half: rows wm*64..+63
    const int wn  = wv & 1;                 // code half: codes wn*64..+63
    const int wg  = blockIdx.x;
    const int r0    = (wg >> 3) * 128;
    const int ch    = wg & 7;               // chunk == XCD
    const int cbase = ch * 1024;

    const char* zhp = (const char*)zh;
    const char* zlp = (const char*)zl;
    const char* ehp = (const char*)eh;
    const char* elp = (const char*)el;

    // enorm slice -> LDS via normal load + ds_write (no vmcnt-queue pollution)
    {
        float4 ev = *reinterpret_cast<const float4*>(enorm + cbase + tid * 4);
        *reinterpret_cast<float4*>(lds + 65536 + tid * 16) = ev;
    }

    // per-thread stage source byte-bases (loop-invariant); per-step offsets are
    // uniform shifts: e += (s&7)<<19 | (s>>3)<<11 ; z += (s&7)<<20
    const int tsw = tid >> 7, tix = tid & 127;
    const size_t E0a = ((size_t)tsw       * K_CODES + cbase + tix) * 16;
    const size_t E0b = ((size_t)(tsw + 2) * K_CODES + cbase + tix) * 16;
    const size_t Z0a = ((size_t)tsw       * N_ROWS  + r0   + tix) * 16;
    const size_t Z0b = ((size_t)(tsw + 2) * N_ROWS  + r0   + tix) * 16;

    auto stage = [&](int s, int b) {
        char* dst = (char*)lds + b * 32768 + tid * 16;
        const size_t ue = (((size_t)(s & 7)) << 19) + (((size_t)(s >> 3)) << 11);
        const size_t uz = ((size_t)(s & 7)) << 20;
        gl2lds16(ehp + E0a + ue, dst);
        gl2lds16(ehp + E0b + ue, dst + 4096);
        gl2lds16(elp + E0a + ue, dst + 8192);
        gl2lds16(elp + E0b + ue, dst + 12288);
        gl2lds16(zhp + Z0a + uz, dst + 16384);
        gl2lds16(zhp + Z0b + uz, dst + 20480);
        gl2lds16(zlp + Z0a + uz, dst + 24576);
        gl2lds16(zlp + Z0b + uz, dst + 28672);
    };

    u64 t1[4], t2[4];                       // top-2 per owned row-tile j
    #pragma unroll
    for (int j = 0; j < 4; ++j) { t1[j] = ~0ULL; t2[j] = ~0ULL; }

    f4v acc[4][4];
    #pragma unroll
    for (int i = 0; i < 4; ++i)
        #pragma unroll
        for (int j = 0; j < 4; ++j)
            acc[i][j] = (f4v){0.f, 0.f, 0.f, 0.f};

    stage(0, 0);
    __syncthreads();                        // prologue: buf0 (and enorm LDS) ready

    for (int s = 0; s < 64; ++s) {
        const int b = s & 1;
        if (s < 63) stage(s + 1, b ^ 1);    // prefetch next step into other buffer

        const char* base = (const char*)lds + b * 32768;
        s8v zhf[4], zlf[4];
        #pragma unroll
        for (int j = 0; j < 4; ++j) {
            int row = wm * 64 + j * 16 + lr;
            zhf[j] = *reinterpret_cast<const s8v*>(base + 16384 + lg * 2048 + row * 16);
            zlf[j] = *reinterpret_cast<const s8v*>(base + 24576 + lg * 2048 + row * 16);
        }
        #pragma unroll
        for (int i = 0; i < 4; ++i) {
            int code = wn * 64 + i * 16 + lr;
            s8v ehf = *reinterpret_cast<const s8v*>(base + lg * 2048 + code * 16);
            s8v elf = *reinterpret_cast<const s8v*>(base + 8192 + lg * 2048 + code * 16);
            #pragma unroll
            for (int j = 0; j < 4; ++j) {
                acc[i][j] = __builtin_amdgcn_mfma_f32_16x16x32_bf16(ehf, zhf[j], acc[i][j], 0, 0, 0);
                acc[i][j] = __builtin_amdgcn_mfma_f32_16x16x32_bf16(elf, zhf[j], acc[i][j], 0, 0, 0);
                acc[i][j] = __builtin_amdgcn_mfma_f32_16x16x32_bf16(ehf, zlf[j], acc[i][j], 0, 0, 0);
            }
        }

        if ((s & 7) == 7) {
            // epilogue for ct = s>>3: dist = enorm - 2*dot (enorm from LDS),
            // fp32 (value,slot) tournament top-2 per row j, then u64 key merge.
            const int cbl = (s >> 3) * 128;
            const int cb  = cbase + cbl;
            float en[16];
            #pragma unroll
            for (int i = 0; i < 4; ++i)
                #pragma unroll
                for (int r = 0; r < 4; ++r)
                    en[i * 4 + r] = *reinterpret_cast<const float*>(
                        lds + 65536 + (cbl + wn * 64 + i * 16 + lg * 4 + r) * 4);
            #pragma unroll
            for (int j = 0; j < 4; ++j) {
                float v1[8], v2[8]; int g1[8], g2[8];
                #pragma unroll
                for (int k = 0; k < 8; ++k) {
                    int a = 2 * k, c = 2 * k + 1;
                    float da = fmaf(-2.f, acc[a >> 2][j][a & 3], en[a]);
                    float dc = fmaf(-2.f, acc[c >> 2][j][c & 3], en[c]);
                    bool w = dc < da;                 // strict: tie -> smaller slot
                    v1[k] = w ? dc : da; g1[k] = w ? c : a;
                    v2[k] = w ? da : dc; g2[k] = w ? a : c;
                }
                #pragma unroll
                for (int st = 4; st >= 1; st >>= 1)
                    #pragma unroll
                    for (int m = 0; m < st; ++m) {
                        float b1 = v1[m + st], b2 = v2[m + st];
                        int  b1s = g1[m + st], b2s = g2[m + st];
                        bool c1 = b1 < v1[m];
                        float hv = c1 ? v1[m] : b1;  int hs = c1 ? g1[m] : b1s;
                        v1[m] = c1 ? b1 : v1[m];     g1[m] = c1 ? b1s : g1[m];
                        bool c2 = b2 < v2[m];
                        float mv = c2 ? b2 : v2[m];  int ms = c2 ? b2s : g2[m];
                        bool c3 = mv < hv;
                        v2[m] = c3 ? mv : hv;        g2[m] = c3 ? ms : hs;
                    }
                int s1 = g1[0], s2 = g2[0];
                u32 code1 = (u32)(cb + wn * 64 + ((s1 >> 2) << 4) + lg * 4 + (s1 & 3));
                u32 code2 = (u32)(cb + wn * 64 + ((s2 >> 2) << 4) + lg * 4 + (s2 & 3));
                u64 k1 = ((u64)f2ord(v1[0]) << 32) | code1;
                u64 k2 = ((u64)f2ord(v2[0]) << 32) | code2;
                u64 n1 = k1 < t1[j] ? k1 : t1[j];
                u64 hi = k1 < t1[j] ? t1[j] : k1;
                u64 m2 = k2 < t2[j] ? k2 : t2[j];
                t1[j] = n1;
                t2[j] = hi < m2 ? hi : m2;
            }
            #pragma unroll
            for (int i = 0; i < 4; ++i)
                #pragma unroll
                for (int j = 0; j < 4; ++j)
                    acc[i][j] = (f4v){0.f, 0.f, 0.f, 0.f};
        }

        __syncthreads();                    // drains prefetch + read fence
    }

    // cross-lane (lg) top-2 merge: lanes sharing (j, lr) hold same z-row
    #pragma unroll
    for (int j = 0; j < 4; ++j) {
        u64 a1 = t1[j], a2 = t2[j];
        #pragma unroll
        for (int mk = 16; mk <= 32; mk <<= 1) {
            u64 o1 = __shfl_xor(a1, mk);
            u64 o2 = __shfl_xor(a2, mk);
            u64 n1 = a1 < o1 ? a1 : o1;
            u64 hi = a1 < o1 ? o1 : a1;
            u64 m2 = a2 < o2 ? a2 : o2;
            a1 = n1;
            a2 = hi < m2 ? hi : m2;
        }
        t1[j] = a1; t2[j] = a2;
    }

    // cross-wave (wn) merge via LDS, then write cand[row][ch][2]
    __syncthreads();
    u64* mbuf = (u64*)lds;                   // 2KB reuse
    if (wn == 1 && lg == 0) {
        #pragma unroll
        for (int j = 0; j < 4; ++j) {
            int s = ((wm * 4 + j) * 16 + lr) * 2;
            mbuf[s] = t1[j]; mbuf[s + 1] = t2[j];
        }
    }
    __syncthreads();
    if (wn == 0 && lg == 0) {
        #pragma unroll
        for (int j = 0; j < 4; ++j) {
            int s = ((wm * 4 + j) * 16 + lr) * 2;
            u64 b1 = mbuf[s], b2 = mbuf[s + 1];
            u64 n1 = t1[j] < b1 ? t1[j] : b1;
            u64 hi = t1[j] < b1 ? b1 : t1[j];
            u64 m2 = t2[j] < b2 ? t2[j] : b2;
            u64 n2 = hi < m2 ? hi : m2;
            int row = r0 + wm * 64 + j * 16 + lr;
            cand[((size_t)row * NCHUNK + ch) * 2]     = n1;
            cand[((size_t)row * NCHUNK + ch) * 2 + 1] = n2;
        }
    }
}

// ---------------- exact fp32 rescore of 16 candidates + outputs ----------------
__global__ __launch_bounds__(256) void rescore_kernel(const float* __restrict__ z,
                                                      const float* __restrict__ emb,
                                                      const float* __restrict__ enorm,
                                                      const u64* __restrict__ cand,
                                                      float* __restrict__ out,
                                                      float* __restrict__ partials) {
    int row  = blockIdx.x * 4 + (threadIdx.x >> 6);
    int lane = threadIdx.x & 63;
    float4 zv = reinterpret_cast<const float4*>(z)[(size_t)row * 64 + lane];

    u64 best = ~0ULL;
    for (int s = 0; s < 2 * NCHUNK; ++s) {
        u32 c = ((u32)cand[(size_t)row * (2 * NCHUNK) + s]) & (K_CODES - 1);
        float4 ev = reinterpret_cast<const float4*>(emb)[(size_t)c * 64 + lane];
        float p = zv.x * ev.x + zv.y * ev.y + zv.z * ev.z + zv.w * ev.w;
        #pragma unroll
        for (int mk = 1; mk < 64; mk <<= 1) p += __shfl_xor(p, mk);
        float dist = fmaf(-2.f, p, enorm[c]);
        u64 key = ((u64)f2ord(dist) << 32) | c;
        best = key < best ? key : best;
    }
    u32 idx = ((u32)best) & (K_CODES - 1);
    if (lane == 0) out[IDX_OFF + row] = (float)idx;

    float4 ev = reinterpret_cast<const float4*>(emb)[(size_t)idx * 64 + lane];
    float tx = ev.x - zv.x, ty = ev.y - zv.y, tz = ev.z - zv.z, tw = ev.w - zv.w;
    float4 o;
    o.x = zv.x + tx; o.y = zv.y + ty; o.z = zv.z + tz; o.w = zv.w + tw;  // straight-through
    reinterpret_cast<float4*>(out)[(size_t)row * 64 + lane] = o;

    float s = tx * tx + ty * ty + tz * tz + tw * tw;
    #pragma unroll
    for (int off = 32; off >= 1; off >>= 1) s += __shfl_down(s, off);

    __shared__ float wsum[4];
    if (lane == 0) wsum[threadIdx.x >> 6] = s;
    __syncthreads();
    if (threadIdx.x == 0)
        partials[blockIdx.x] = (wsum[0] + wsum[1]) + (wsum[2] + wsum[3]);
}

__global__ __launch_bounds__(256) void loss_kernel(const float* __restrict__ partials,
                                                   float* __restrict__ out) {
    __shared__ float sm[256];
    float s = 0.0f;
    for (int i = threadIdx.x; i < 4096; i += 256) s += partials[i];
    sm[threadIdx.x] = s;
    __syncthreads();
    #pragma unroll
    for (int st = 128; st >= 1; st >>= 1) {
        if (threadIdx.x < st) sm[threadIdx.x] += sm[threadIdx.x + st];
        __syncthreads();
    }
    if (threadIdx.x == 0)
        out[LOSS_OFF] = sm[0] * (0.25f / (float)(N_ROWS * D_DIM));
}

extern "C" void kernel_launch(void* const* d_in, const int* in_sizes, int n_in,
                              void* d_out, int out_size, void* d_ws, size_t ws_size,
                              hipStream_t stream) {
    const float* z   = (const float*)d_in[0];
    const float* emb = (const float*)d_in[1];
    float* out = (float*)d_out;

    u64*   cand     = (u64*)d_ws;
    float* enorm    = (float*)((char*)d_ws + WS_ENORM_OFF);
    float* partials = (float*)((char*)d_ws + WS_PARTIAL_OFF);
    unsigned short* zh = (unsigned short*)((char*)d_ws + WS_ZH_OFF);
    unsigned short* zl = (unsigned short*)((char*)d_ws + WS_ZL_OFF);
    unsigned short* eh = (unsigned short*)((char*)d_ws + WS_EH_OFF);
    unsigned short* el = (unsigned short*)((char*)d_ws + WS_EL_OFF);

    zconv_kernel<<<4096, 256, 0, stream>>>(z, zh, zl);
    econv_kernel<<<2048, 256, 0, stream>>>(emb, eh, el, enorm);
    argmin_kernel<<<1024, 256, 0, stream>>>(zh, zl, eh, el, enorm, cand);
    rescore_kernel<<<N_ROWS / 4, 256, 0, stream>>>(z, emb, enorm, cand, out, partials);
    loss_kernel<<<1, 256, 0, stream>>>(partials, out);
}

// Round 15
// 245.419 us; speedup vs baseline: 1.5579x; 1.1068x over previous
//
#include <hip/hip_runtime.h>
#include <math.h>

#define D_DIM   256
#define N_ROWS  16384
#define K_CODES 8192
#define NCHUNK  8          // 8 chunks of 1024 codes; chunk -> XCD

typedef __attribute__((ext_vector_type(8))) short s8v;           // 8 bf16 (A/B frag)
typedef __attribute__((ext_vector_type(4))) float f4v;           // 4 f32  (C/D frag)
typedef __attribute__((ext_vector_type(4))) unsigned short us4;  // 4 bf16 (8B write)
typedef unsigned long long u64;
typedef unsigned int u32;

// out layout: [0, 4194304) z_q_st | [4194304, 4210688) indices (as float) | [4210688] vq_loss
#define IDX_OFF  ((size_t)N_ROWS * D_DIM)
#define LOSS_OFF (IDX_OFF + N_ROWS)

// ws layout (27 MB used):
//   [0, 2MB)        u64 cand[N_ROWS][NCHUNK][2]
//   [2MB, +32KB)    float enorm[8192]
//   [+32KB, +16KB)  float partials[4096]
//   [3MB, 11MB)     bf16 zh_t  K-major: [d0b][lg][row][16B]  (d0b<8, lg<4)
//   [11MB, 19MB)    bf16 zl_t  same
//   [19MB, 23MB)    bf16 eh_t  [d0b][lg][code][16B]
//   [23MB, 27MB)    bf16 el_t  same
#define WS_ENORM_OFF    (2u * 1024u * 1024u)
#define WS_PARTIAL_OFF  (WS_ENORM_OFF + 32768u)
#define WS_ZH_OFF       (3u * 1024u * 1024u)
#define WS_ZL_OFF       (11u * 1024u * 1024u)
#define WS_EH_OFF       (19u * 1024u * 1024u)
#define WS_EL_OFF       (23u * 1024u * 1024u)

__device__ __forceinline__ unsigned short f2bf(float f) {   // fp32 -> bf16 RNE
    u32 u = __float_as_uint(f);
    return (unsigned short)((u + 0x7fffu + ((u >> 16) & 1u)) >> 16);
}
__device__ __forceinline__ float bf2f(unsigned short b) {
    return __uint_as_float(((u32)b) << 16);
}
__device__ __forceinline__ u32 f2ord(float f) {             // monotonic fp32 -> u32
    u32 u = __float_as_uint(f);
    return (u & 0x80000000u) ? ~u : (u | 0x80000000u);
}
__device__ __forceinline__ void gl2lds16(const void* g, void* l) {
    __builtin_amdgcn_global_load_lds(
        (const __attribute__((address_space(1))) unsigned int*)g,
        (__attribute__((address_space(3))) unsigned int*)l, 16, 0, 0);
}

// ---- pre-convert: z -> zh_t, zl_t (K-major tiling) ----
__global__ __launch_bounds__(256) void zconv_kernel(const float* __restrict__ z,
                                                    unsigned short* __restrict__ zh,
                                                    unsigned short* __restrict__ zl) {
    int q = blockIdx.x * 256 + threadIdx.x;        // float4 index, 0..1048575
    float4 v = reinterpret_cast<const float4*>(z)[q];
    us4 h, lo;
    h[0] = f2bf(v.x); lo[0] = f2bf(v.x - bf2f(h[0]));
    h[1] = f2bf(v.y); lo[1] = f2bf(v.y - bf2f(h[1]));
    h[2] = f2bf(v.z); lo[2] = f2bf(v.z - bf2f(h[2]));
    h[3] = f2bf(v.w); lo[3] = f2bf(v.w - bf2f(h[3]));
    int row = q >> 6;                               // 64 float4 per row
    int f   = q & 63;                               // d = f*4 .. f*4+3
    int d0b = f >> 3, lg = (f >> 1) & 3, half = f & 1;
    size_t off = ((size_t)(d0b * 4 + lg) * N_ROWS + row) * 16 + half * 8;
    *reinterpret_cast<us4*>((char*)zh + off) = h;
    *reinterpret_cast<us4*>((char*)zl + off) = lo;
}

// ---- pre-convert: emb -> eh_t, el_t (K-major tiling) + enorm (fused) ----
__global__ __launch_bounds__(256) void econv_kernel(const float* __restrict__ emb,
                                                    unsigned short* __restrict__ eh,
                                                    unsigned short* __restrict__ el,
                                                    float* __restrict__ enorm) {
    int q = blockIdx.x * 256 + threadIdx.x;        // 0..524287
    float4 v = reinterpret_cast<const float4*>(emb)[q];

    // one wave == one codebook row (64 lanes x 4 floats): fused enorm
    float s = v.x * v.x + v.y * v.y + v.z * v.z + v.w * v.w;
    #pragma unroll
    for (int off = 32; off >= 1; off >>= 1) s += __shfl_down(s, off);

    us4 h, lo;
    h[0] = f2bf(v.x); lo[0] = f2bf(v.x - bf2f(h[0]));
    h[1] = f2bf(v.y); lo[1] = f2bf(v.y - bf2f(h[1]));
    h[2] = f2bf(v.z); lo[2] = f2bf(v.z - bf2f(h[2]));
    h[3] = f2bf(v.w); lo[3] = f2bf(v.w - bf2f(h[3]));
    int row = q >> 6;
    int f   = q & 63;
    if (f == 0) enorm[row] = s;
    int d0b = f >> 3, lg = (f >> 1) & 3, half = f & 1;
    size_t off = ((size_t)(d0b * 4 + lg) * K_CODES + row) * 16 + half * 8;
    *reinterpret_cast<us4*>((char*)eh + off) = h;
    *reinterpret_cast<us4*>((char*)el + off) = lo;
}

// ---------------- MFMA argmin: e-only LDS staging, z in registers ----------------
// Block: 128 codes x 128 rows per ct-step; 4 waves (wm,wn) 2x2, each 64x64.
// e staged via gl2lds (16KB/step, dbuf 32KB, L2-resident chunk -> short latency,
// covered by MFMA phase). z frags loaded global->reg ONE STEP AHEAD (zA/zB named
// sets, 2-step unrolled loop, static indexing) -> full-step latency cover.
// enorm slice in LDS at +32768 (lgkm-side). Round-12 sync structure (one
// __syncthreads per step).
__global__ __launch_bounds__(256, 2) void argmin_kernel(const unsigned short* __restrict__ zh,
                                                        const unsigned short* __restrict__ zl,
                                                        const unsigned short* __restrict__ eh,
                                                        const unsigned short* __restrict__ el,
                                                        const float* __restrict__ enorm,
                                                        u64* __restrict__ cand) {
    __shared__ __align__(16) unsigned char lds[36864];   // 2x16KB e-dbuf + 4KB enorm

    const int tid = threadIdx.x;
    const int wv  = tid >> 6;
    const int l   = tid & 63;
    const int lr  = l & 15;
    const int lg  = l >> 4;
    const int wm  = wv >> 1;                // row half: rows wm*64..+63
    const int wn  = wv & 1;                 // code half: codes wn*64..+63
    const int wg  = blockIdx.x;
    const int r0    = (wg >> 3) * 128;
    const int ch    = wg & 7;               // chunk == XCD
    const int cbase = ch * 1024;

    const char* zhp = (const char*)zh;
    const char* zlp = (const char*)zl;
    const char* ehp = (const char*)eh;
    const char* elp = (const char*)el;

    // enorm slice -> LDS via normal load + ds_write (no vmcnt-queue pollution)
    {
        float4 ev = *reinterpret_cast<const float4*>(enorm + cbase + tid * 4);
        *reinterpret_cast<float4*>(lds + 32768 + tid * 16) = ev;
    }

    // e-stage per-thread source bases; per-step uniform offset (s&7)<<19 | (s>>3)<<11
    const int tsw = tid >> 7, tix = tid & 127;
    const size_t E0a = ((size_t)tsw       * K_CODES + cbase + tix) * 16;
    const size_t E0b = ((size_t)(tsw + 2) * K_CODES + cbase + tix) * 16;

    auto stage = [&](int s, int b) {
        char* dst = (char*)lds + b * 16384 + tid * 16;
        const size_t ue = (((size_t)(s & 7)) << 19) + (((size_t)(s >> 3)) << 11);
        gl2lds16(ehp + E0a + ue, dst);
        gl2lds16(ehp + E0b + ue, dst + 4096);
        gl2lds16(elp + E0a + ue, dst + 8192);
        gl2lds16(elp + E0b + ue, dst + 12288);
    };

    // z-frag per-thread byte bases (d0b stride = 1MB = 1<<20)
    size_t Zb[4];
    #pragma unroll
    for (int j = 0; j < 4; ++j)
        Zb[j] = ((size_t)lg * N_ROWS + r0 + wm * 64 + j * 16 + lr) * 16;

    u64 t1[4], t2[4];                       // top-2 per owned row-tile j
    #pragma unroll
    for (int j = 0; j < 4; ++j) { t1[j] = ~0ULL; t2[j] = ~0ULL; }

    f4v acc[4][4];
    #pragma unroll
    for (int i = 0; i < 4; ++i)
        #pragma unroll
        for (int j = 0; j < 4; ++j)
            acc[i][j] = (f4v){0.f, 0.f, 0.f, 0.f};

    s8v zhA[4], zlA[4], zhB[4], zlB[4];
    // prologue: zA for step 0 (d0b=0); e-stage step 0
    #pragma unroll
    for (int j = 0; j < 4; ++j) {
        zhA[j] = *reinterpret_cast<const s8v*>(zhp + Zb[j]);
        zlA[j] = *reinterpret_cast<const s8v*>(zlp + Zb[j]);
    }
    stage(0, 0);
    __syncthreads();                        // buf0 + enorm ready

    for (int sp = 0; sp < 64; sp += 2) {
        // ---- step sp (even): e-buf 0, compute with zA; prefetch step sp+1 ----
        stage(sp + 1, 1);
        {
            size_t off = ((size_t)((sp + 1) & 7)) << 20;
            #pragma unroll
            for (int j = 0; j < 4; ++j) {
                zhB[j] = *reinterpret_cast<const s8v*>(zhp + Zb[j] + off);
                zlB[j] = *reinterpret_cast<const s8v*>(zlp + Zb[j] + off);
            }
        }
        {
            const char* base = (const char*)lds;             // buf 0
            #pragma unroll
            for (int i = 0; i < 4; ++i) {
                int code = wn * 64 + i * 16 + lr;
                s8v ehf = *reinterpret_cast<const s8v*>(base + lg * 2048 + code * 16);
                s8v elf = *reinterpret_cast<const s8v*>(base + 8192 + lg * 2048 + code * 16);
                #pragma unroll
                for (int j = 0; j < 4; ++j) {
                    acc[i][j] = __builtin_amdgcn_mfma_f32_16x16x32_bf16(ehf, zhA[j], acc[i][j], 0, 0, 0);
                    acc[i][j] = __builtin_amdgcn_mfma_f32_16x16x32_bf16(elf, zhA[j], acc[i][j], 0, 0, 0);
                    acc[i][j] = __builtin_amdgcn_mfma_f32_16x16x32_bf16(ehf, zlA[j], acc[i][j], 0, 0, 0);
                }
            }
        }
        __syncthreads();                    // drains e-prefetch(sp+1) + zB loads

        // ---- step sp+1 (odd): e-buf 1, compute with zB; prefetch step sp+2 ----
        if (sp + 2 < 64) {
            stage(sp + 2, 0);
            size_t off = ((size_t)((sp + 2) & 7)) << 20;
            #pragma unroll
            for (int j = 0; j < 4; ++j) {
                zhA[j] = *reinterpret_cast<const s8v*>(zhp + Zb[j] + off);
                zlA[j] = *reinterpret_cast<const s8v*>(zlp + Zb[j] + off);
            }
        }
        {
            const char* base = (const char*)lds + 16384;     // buf 1
            #pragma unroll
            for (int i = 0; i < 4; ++i) {
                int code = wn * 64 + i * 16 + lr;
                s8v ehf = *reinterpret_cast<const s8v*>(base + lg * 2048 + code * 16);
                s8v elf = *reinterpret_cast<const s8v*>(base + 8192 + lg * 2048 + code * 16);
                #pragma unroll
                for (int j = 0; j < 4; ++j) {
                    acc[i][j] = __builtin_amdgcn_mfma_f32_16x16x32_bf16(ehf, zhB[j], acc[i][j], 0, 0, 0);
                    acc[i][j] = __builtin_amdgcn_mfma_f32_16x16x32_bf16(elf, zhB[j], acc[i][j], 0, 0, 0);
                    acc[i][j] = __builtin_amdgcn_mfma_f32_16x16x32_bf16(ehf, zlB[j], acc[i][j], 0, 0, 0);
                }
            }
        }

        if (((sp + 1) & 7) == 7) {
            // epilogue for ct = (sp+1)>>3: dist = enorm - 2*dot (enorm from LDS),
            // fp32 (value,slot) tournament top-2 per row j, then u64 key merge.
            const int cbl = ((sp + 1) >> 3) * 128;
            const int cb  = cbase + cbl;
            float en[16];
            #pragma unroll
            for (int i = 0; i < 4; ++i)
                #pragma unroll
                for (int r = 0; r < 4; ++r)
                    en[i * 4 + r] = *reinterpret_cast<const float*>(
                        lds + 32768 + (cbl + wn * 64 + i * 16 + lg * 4 + r) * 4);
            #pragma unroll
            for (int j = 0; j < 4; ++j) {
                float v1[8], v2[8]; int g1[8], g2[8];
                #pragma unroll
                for (int k = 0; k < 8; ++k) {
                    int a = 2 * k, c = 2 * k + 1;
                    float da = fmaf(-2.f, acc[a >> 2][j][a & 3], en[a]);
                    float dc = fmaf(-2.f, acc[c >> 2][j][c & 3], en[c]);
                    bool w = dc < da;                 // strict: tie -> smaller slot
                    v1[k] = w ? dc : da; g1[k] = w ? c : a;
                    v2[k] = w ? da : dc; g2[k] = w ? a : c;
                }
                #pragma unroll
                for (int st = 4; st >= 1; st >>= 1)
                    #pragma unroll
                    for (int m = 0; m < st; ++m) {
                        float b1 = v1[m + st], b2 = v2[m + st];
                        int  b1s = g1[m + st], b2s = g2[m + st];
                        bool c1 = b1 < v1[m];
                        float hv = c1 ? v1[m] : b1;  int hs = c1 ? g1[m] : b1s;
                        v1[m] = c1 ? b1 : v1[m];     g1[m] = c1 ? b1s : g1[m];
                        bool c2 = b2 < v2[m];
                        float mv = c2 ? b2 : v2[m];  int ms = c2 ? b2s : g2[m];
                        bool c3 = mv < hv;
                        v2[m] = c3 ? mv : hv;        g2[m] = c3 ? ms : hs;
                    }
                int s1 = g1[0], s2 = g2[0];
                u32 code1 = (u32)(cb + wn * 64 + ((s1 >> 2) << 4) + lg * 4 + (s1 & 3));
                u32 code2 = (u32)(cb + wn * 64 + ((s2 >> 2) << 4) + lg * 4 + (s2 & 3));
                u64 k1 = ((u64)f2ord(v1[0]) << 32) | code1;
                u64 k2 = ((u64)f2ord(v2[0]) << 32) | code2;
                u64 n1 = k1 < t1[j] ? k1 : t1[j];
                u64 hi = k1 < t1[j] ? t1[j] : k1;
                u64 m2 = k2 < t2[j] ? k2 : t2[j];
                t1[j] = n1;
                t2[j] = hi < m2 ? hi : m2;
            }
            #pragma unroll
            for (int i = 0; i < 4; ++i)
                #pragma unroll
                for (int j = 0; j < 4; ++j)
                    acc[i][j] = (f4v){0.f, 0.f, 0.f, 0.f};
        }

        __syncthreads();                    // drains e-prefetch(sp+2) + zA loads
    }

    // cross-lane (lg) top-2 merge: lanes sharing (j, lr) hold same z-row
    #pragma unroll
    for (int j = 0; j < 4; ++j) {
        u64 a1 = t1[j], a2 = t2[j];
        #pragma unroll
        for (int mk = 16; mk <= 32; mk <<= 1) {
            u64 o1 = __shfl_xor(a1, mk);
            u64 o2 = __shfl_xor(a2, mk);
            u64 n1 = a1 < o1 ? a1 : o1;
            u64 hi = a1 < o1 ? o1 : a1;
            u64 m2 = a2 < o2 ? a2 : o2;
            a1 = n1;
            a2 = hi < m2 ? hi : m2;
        }
        t1[j] = a1; t2[j] = a2;
    }

    // cross-wave (wn) merge via LDS, then write cand[row][ch][2]
    __syncthreads();
    u64* mbuf = (u64*)lds;                   // 2KB reuse
    if (wn == 1 && lg == 0) {
        #pragma unroll
        for (int j = 0; j < 4; ++j) {
            int s = ((wm * 4 + j) * 16 + lr) * 2;
            mbuf[s] = t1[j]; mbuf[s + 1] = t2[j];
        }
    }
    __syncthreads();
    if (wn == 0 && lg == 0) {
        #pragma unroll
        for (int j = 0; j < 4; ++j) {
            int s = ((wm * 4 + j) * 16 + lr) * 2;
            u64 b1 = mbuf[s], b2 = mbuf[s + 1];
            u64 n1 = t1[j] < b1 ? t1[j] : b1;
            u64 hi = t1[j] < b1 ? b1 : t1[j];
            u64 m2 = t2[j] < b2 ? t2[j] : b2;
            u64 n2 = hi < m2 ? hi : m2;
            int row = r0 + wm * 64 + j * 16 + lr;
            cand[((size_t)row * NCHUNK + ch) * 2]     = n1;
            cand[((size_t)row * NCHUNK + ch) * 2 + 1] = n2;
        }
    }
}

// ---------------- exact fp32 rescore of 16 candidates + outputs ----------------
__global__ __launch_bounds__(256) void rescore_kernel(const float* __restrict__ z,
                                                      const float* __restrict__ emb,
                                                      const float* __restrict__ enorm,
                                                      const u64* __restrict__ cand,
                                                      float* __restrict__ out,
                                                      float* __restrict__ partials) {
    int row  = blockIdx.x * 4 + (threadIdx.x >> 6);
    int lane = threadIdx.x & 63;
    float4 zv = reinterpret_cast<const float4*>(z)[(size_t)row * 64 + lane];

    u64 best = ~0ULL;
    for (int s = 0; s < 2 * NCHUNK; ++s) {
        u32 c = ((u32)cand[(size_t)row * (2 * NCHUNK) + s]) & (K_CODES - 1);
        float4 ev = reinterpret_cast<const float4*>(emb)[(size_t)c * 64 + lane];
        float p = zv.x * ev.x + zv.y * ev.y + zv.z * ev.z + zv.w * ev.w;
        #pragma unroll
        for (int mk = 1; mk < 64; mk <<= 1) p += __shfl_xor(p, mk);
        float dist = fmaf(-2.f, p, enorm[c]);
        u64 key = ((u64)f2ord(dist) << 32) | c;
        best = key < best ? key : best;
    }
    u32 idx = ((u32)best) & (K_CODES - 1);
    if (lane == 0) out[IDX_OFF + row] = (float)idx;

    float4 ev = reinterpret_cast<const float4*>(emb)[(size_t)idx * 64 + lane];
    float tx = ev.x - zv.x, ty = ev.y - zv.y, tz = ev.z - zv.z, tw = ev.w - zv.w;
    float4 o;
    o.x = zv.x + tx; o.y = zv.y + ty; o.z = zv.z + tz; o.w = zv.w + tw;  // straight-through
    reinterpret_cast<float4*>(out)[(size_t)row * 64 + lane] = o;

    float s = tx * tx + ty * ty + tz * tz + tw * tw;
    #pragma unroll
    for (int off = 32; off >= 1; off >>= 1) s += __shfl_down(s, off);

    __shared__ float wsum[4];
    if (lane == 0) wsum[threadIdx.x >> 6] = s;
    __syncthreads();
    if (threadIdx.x == 0)
        partials[blockIdx.x] = (wsum[0] + wsum[1]) + (wsum[2] + wsum[3]);
}

__global__ __launch_bounds__(256) void loss_kernel(const float* __restrict__ partials,
                                                   float* __restrict__ out) {
    __shared__ float sm[256];
    float s = 0.0f;
    for (int i = threadIdx.x; i < 4096; i += 256) s += partials[i];
    sm[threadIdx.x] = s;
    __syncthreads();
    #pragma unroll
    for (int st = 128; st >= 1; st >>= 1) {
        if (threadIdx.x < st) sm[threadIdx.x] += sm[threadIdx.x + st];
        __syncthreads();
    }
    if (threadIdx.x == 0)
        out[LOSS_OFF] = sm[0] * (0.25f / (float)(N_ROWS * D_DIM));
}

extern "C" void kernel_launch(void* const* d_in, const int* in_sizes, int n_in,
                              void* d_out, int out_size, void* d_ws, size_t ws_size,
                              hipStream_t stream) {
    const float* z   = (const float*)d_in[0];
    const float* emb = (const float*)d_in[1];
    float* out = (float*)d_out;

    u64*   cand     = (u64*)d_ws;
    float* enorm    = (float*)((char*)d_ws + WS_ENORM_OFF);
    float* partials = (float*)((char*)d_ws + WS_PARTIAL_OFF);
    unsigned short* zh = (unsigned short*)((char*)d_ws + WS_ZH_OFF);
    unsigned short* zl = (unsigned short*)((char*)d_ws + WS_ZL_OFF);
    unsigned short* eh = (unsigned short*)((char*)d_ws + WS_EH_OFF);
    unsigned short* el = (unsigned short*)((char*)d_ws + WS_EL_OFF);

    zconv_kernel<<<4096, 256, 0, stream>>>(z, zh, zl);
    econv_kernel<<<2048, 256, 0, stream>>>(emb, eh, el, enorm);
    argmin_kernel<<<1024, 256, 0, stream>>>(zh, zl, eh, el, enorm, cand);
    rescore_kernel<<<N_ROWS / 4, 256, 0, stream>>>(z, emb, enorm, cand, out, partials);
    loss_kernel<<<1, 256, 0, stream>>>(partials, out);
}

// Round 18
// 233.058 us; speedup vs baseline: 1.6406x; 1.0530x over previous
//
#include <hip/hip_runtime.h>
#include <math.h>

#define D_DIM   256
#define N_ROWS  16384
#define K_CODES 8192
#define NCHUNK  8          // 8 chunks of 1024 codes

typedef __attribute__((ext_vector_type(8))) short s8v;           // 8 bf16 (A/B frag)
typedef __attribute__((ext_vector_type(4))) float f4v;           // 4 f32  (C/D frag)
typedef __attribute__((ext_vector_type(4))) unsigned short us4;  // 4 bf16 (8B write)
typedef unsigned long long u64;
typedef unsigned int u32;

// out layout: [0, 4194304) z_q_st | [4194304, 4210688) indices (as float) | [4210688] vq_loss
#define IDX_OFF  ((size_t)N_ROWS * D_DIM)
#define LOSS_OFF (IDX_OFF + N_ROWS)

// ws layout (27 MB used):
//   [0, 2MB)        u64 cand[N_ROWS][NCHUNK][2]
//   [2MB, +32KB)    float enorm[8192]
//   [+32KB, +16KB)  float partials[4096]
//   [3MB, 11MB)     bf16 zh_t  K-major: [d0b][lg][row][16B]  (d0b<8, lg<4)
//   [11MB, 19MB)    bf16 zl_t  same
//   [19MB, 23MB)    bf16 eh_t  [d0b][lg][code][16B]
//   [23MB, 27MB)    bf16 el_t  same
#define WS_ENORM_OFF    (2u * 1024u * 1024u)
#define WS_PARTIAL_OFF  (WS_ENORM_OFF + 32768u)
#define WS_ZH_OFF       (3u * 1024u * 1024u)
#define WS_ZL_OFF       (11u * 1024u * 1024u)
#define WS_EH_OFF       (19u * 1024u * 1024u)
#define WS_EL_OFF       (23u * 1024u * 1024u)

__device__ __forceinline__ unsigned short f2bf(float f) {   // fp32 -> bf16 RNE
    u32 u = __float_as_uint(f);
    return (unsigned short)((u + 0x7fffu + ((u >> 16) & 1u)) >> 16);
}
__device__ __forceinline__ float bf2f(unsigned short b) {
    return __uint_as_float(((u32)b) << 16);
}
__device__ __forceinline__ u32 f2ord(float f) {             // monotonic fp32 -> u32
    u32 u = __float_as_uint(f);
    return (u & 0x80000000u) ? ~u : (u | 0x80000000u);
}
__device__ __forceinline__ void gl2lds16(const void* g, void* l) {
    __builtin_amdgcn_global_load_lds(
        (const __attribute__((address_space(1))) unsigned int*)g,
        (__attribute__((address_space(3))) unsigned int*)l, 16, 0, 0);
}

// ---- pre-convert: z -> zh_t, zl_t (K-major tiling) ----
__global__ __launch_bounds__(256) void zconv_kernel(const float* __restrict__ z,
                                                    unsigned short* __restrict__ zh,
                                                    unsigned short* __restrict__ zl) {
    int q = blockIdx.x * 256 + threadIdx.x;        // float4 index, 0..1048575
    float4 v = reinterpret_cast<const float4*>(z)[q];
    us4 h, lo;
    h[0] = f2bf(v.x); lo[0] = f2bf(v.x - bf2f(h[0]));
    h[1] = f2bf(v.y); lo[1] = f2bf(v.y - bf2f(h[1]));
    h[2] = f2bf(v.z); lo[2] = f2bf(v.z - bf2f(h[2]));
    h[3] = f2bf(v.w); lo[3] = f2bf(v.w - bf2f(h[3]));
    int row = q >> 6;                               // 64 float4 per row
    int f   = q & 63;                               // d = f*4 .. f*4+3
    int d0b = f >> 3, lg = (f >> 1) & 3, half = f & 1;
    size_t off = ((size_t)(d0b * 4 + lg) * N_ROWS + row) * 16 + half * 8;
    *reinterpret_cast<us4*>((char*)zh + off) = h;
    *reinterpret_cast<us4*>((char*)zl + off) = lo;
}

// ---- pre-convert: emb -> eh_t, el_t (K-major tiling) + enorm (fused) ----
__global__ __launch_bounds__(256) void econv_kernel(const float* __restrict__ emb,
                                                    unsigned short* __restrict__ eh,
                                                    unsigned short* __restrict__ el,
                                                    float* __restrict__ enorm) {
    int q = blockIdx.x * 256 + threadIdx.x;        // 0..524287
    float4 v = reinterpret_cast<const float4*>(emb)[q];

    // one wave == one codebook row (64 lanes x 4 floats): fused enorm
    float s = v.x * v.x + v.y * v.y + v.z * v.z + v.w * v.w;
    #pragma unroll
    for (int off = 32; off >= 1; off >>= 1) s += __shfl_down(s, off);

    us4 h, lo;
    h[0] = f2bf(v.x); lo[0] = f2bf(v.x - bf2f(h[0]));
    h[1] = f2bf(v.y); lo[1] = f2bf(v.y - bf2f(h[1]));
    h[2] = f2bf(v.z); lo[2] = f2bf(v.z - bf2f(h[2]));
    h[3] = f2bf(v.w); lo[3] = f2bf(v.w - bf2f(h[3]));
    int row = q >> 6;
    int f   = q & 63;
    if (f == 0) enorm[row] = s;
    int d0b = f >> 3, lg = (f >> 1) & 3, half = f & 1;
    size_t off = ((size_t)(d0b * 4 + lg) * K_CODES + row) * 16 + half * 8;
    *reinterpret_cast<us4*>((char*)eh + off) = h;
    *reinterpret_cast<us4*>((char*)el + off) = lo;
}

// ---------------- MFMA argmin: e-only LDS staging, z in registers ----------------
// ROUND-16/17/18 CHANGE (only one vs round 15): wg -> (r0, ch) mapping. Each XCD
// (wg&7, dispatch round-robin) owns a 16x8 RECTANGLE of the (row-block x chunk)
// grid:
//   z slice = 2048 rows = 2MB -> L2-resident, shared by 8 blocks per row-slice
//   (kills the 523MB L3 re-read traffic of the 128x1 column mapping);
//   e rotates through 8 chunks, ~32KB hot window each (adjacent launch order).
// Kernel body otherwise byte-identical to the round-15 passing version.
__global__ __launch_bounds__(256, 2) void argmin_kernel(const unsigned short* __restrict__ zh,
                                                        const unsigned short* __restrict__ zl,
                                                        const unsigned short* __restrict__ eh,
                                                        const unsigned short* __restrict__ el,
                                                        const float* __restrict__ enorm,
                                                        u64* __restrict__ cand) {
    __shared__ __align__(16) unsigned char lds[36864];   // 2x16KB e-dbuf + 4KB enorm

    const int tid = threadIdx.x;
    const int wv  = tid >> 6;
    const int l   = tid & 63;
    const int lr  = l & 15;
    const int lg  = l >> 4;
    const int wm  = wv >> 1;                // row half: rows wm*64..+63
    const int wn  = wv & 1;                 // code half: codes wn*64..+63
    const int wg  = blockIdx.x;
    const int x   = wg & 7;                 // XCD (round-robin dispatch)
    const int i   = wg >> 3;                // 0..127 within XCD
    const int ch  = i >> 4;                 // chunk 0..7
    const int r0    = x * 2048 + (i & 15) * 128;   // row-block within XCD's 2048-row slice
    const int cbase = ch * 1024;

    const char* zhp = (const char*)zh;
    const char* zlp = (const char*)zl;
    const char* ehp = (const char*)eh;
    const char* elp = (const char*)el;

    // enorm slice -> LDS via normal load + ds_write (no vmcnt-queue pollution)
    {
        float4 ev = *reinterpret_cast<const float4*>(enorm + cbase + tid * 4);
        *reinterpret_cast<float4*>(lds + 32768 + tid * 16) = ev;
    }

    // e-stage per-thread source bases; per-step uniform offset (s&7)<<19 | (s>>3)<<11
    const int tsw = tid >> 7, tix = tid & 127;
    const size_t E0a = ((size_t)tsw       * K_CODES + cbase + tix) * 16;
    const size_t E0b = ((size_t)(tsw + 2) * K_CODES + cbase + tix) * 16;

    auto stage = [&](int s, int b) {
        char* dst = (char*)lds + b * 16384 + tid * 16;
        const size_t ue = (((size_t)(s & 7)) << 19) + (((size_t)(s >> 3)) << 11);
        gl2lds16(ehp + E0a + ue, dst);
        gl2lds16(ehp + E0b + ue, dst + 4096);
        gl2lds16(elp + E0a + ue, dst + 8192);
        gl2lds16(elp + E0b + ue, dst + 12288);
    };

    // z-frag per-thread byte bases (d0b stride = 1MB = 1<<20)
    size_t Zb[4];
    #pragma unroll
    for (int j = 0; j < 4; ++j)
        Zb[j] = ((size_t)lg * N_ROWS + r0 + wm * 64 + j * 16 + lr) * 16;

    u64 t1[4], t2[4];                       // top-2 per owned row-tile j
    #pragma unroll
    for (int j = 0; j < 4; ++j) { t1[j] = ~0ULL; t2[j] = ~0ULL; }

    f4v acc[4][4];
    #pragma unroll
    for (int i2 = 0; i2 < 4; ++i2)
        #pragma unroll
        for (int j = 0; j < 4; ++j)
            acc[i2][j] = (f4v){0.f, 0.f, 0.f, 0.f};

    s8v zhA[4], zlA[4], zhB[4], zlB[4];
    // prologue: zA for step 0 (d0b=0); e-stage step 0
    #pragma unroll
    for (int j = 0; j < 4; ++j) {
        zhA[j] = *reinterpret_cast<const s8v*>(zhp + Zb[j]);
        zlA[j] = *reinterpret_cast<const s8v*>(zlp + Zb[j]);
    }
    stage(0, 0);
    __syncthreads();                        // buf0 + enorm ready

    for (int sp = 0; sp < 64; sp += 2) {
        // ---- step sp (even): e-buf 0, compute with zA; prefetch step sp+1 ----
        stage(sp + 1, 1);
        {
            size_t off = ((size_t)((sp + 1) & 7)) << 20;
            #pragma unroll
            for (int j = 0; j < 4; ++j) {
                zhB[j] = *reinterpret_cast<const s8v*>(zhp + Zb[j] + off);
                zlB[j] = *reinterpret_cast<const s8v*>(zlp + Zb[j] + off);
            }
        }
        {
            const char* base = (const char*)lds;             // buf 0
            #pragma unroll
            for (int i2 = 0; i2 < 4; ++i2) {
                int code = wn * 64 + i2 * 16 + lr;
                s8v ehf = *reinterpret_cast<const s8v*>(base + lg * 2048 + code * 16);
                s8v elf = *reinterpret_cast<const s8v*>(base + 8192 + lg * 2048 + code * 16);
                #pragma unroll
                for (int j = 0; j < 4; ++j) {
                    acc[i2][j] = __builtin_amdgcn_mfma_f32_16x16x32_bf16(ehf, zhA[j], acc[i2][j], 0, 0, 0);
                    acc[i2][j] = __builtin_amdgcn_mfma_f32_16x16x32_bf16(elf, zhA[j], acc[i2][j], 0, 0, 0);
                    acc[i2][j] = __builtin_amdgcn_mfma_f32_16x16x32_bf16(ehf, zlA[j], acc[i2][j], 0, 0, 0);
                }
            }
        }
        __syncthreads();                    // drains e-prefetch(sp+1) + zB loads

        // ---- step sp+1 (odd): e-buf 1, compute with zB; prefetch step sp+2 ----
        if (sp + 2 < 64) {
            stage(sp + 2, 0);
            size_t off = ((size_t)((sp + 2) & 7)) << 20;
            #pragma unroll
            for (int j = 0; j < 4; ++j) {
                zhA[j] = *reinterpret_cast<const s8v*>(zhp + Zb[j] + off);
                zlA[j] = *reinterpret_cast<const s8v*>(zlp + Zb[j] + off);
            }
        }
        {
            const char* base = (const char*)lds + 16384;     // buf 1
            #pragma unroll
            for (int i2 = 0; i2 < 4; ++i2) {
                int code = wn * 64 + i2 * 16 + lr;
                s8v ehf = *reinterpret_cast<const s8v*>(base + lg * 2048 + code * 16);
                s8v elf = *reinterpret_cast<const s8v*>(base + 8192 + lg * 2048 + code * 16);
                #pragma unroll
                for (int j = 0; j < 4; ++j) {
                    acc[i2][j] = __builtin_amdgcn_mfma_f32_16x16x32_bf16(ehf, zhB[j], acc[i2][j], 0, 0, 0);
                    acc[i2][j] = __builtin_amdgcn_mfma_f32_16x16x32_bf16(elf, zhB[j], acc[i2][j], 0, 0, 0);
                    acc[i2][j] = __builtin_amdgcn_mfma_f32_16x16x32_bf16(ehf, zlB[j], acc[i2][j], 0, 0, 0);
                }
            }
        }

        if (((sp + 1) & 7) == 7) {
            // epilogue for ct = (sp+1)>>3: dist = enorm - 2*dot (enorm from LDS),
            // fp32 (value,slot) tournament top-2 per row j, then u64 key merge.
            const int cbl = ((sp + 1) >> 3) * 128;
            const int cb  = cbase + cbl;
            float en[16];
            #pragma unroll
            for (int i2 = 0; i2 < 4; ++i2)
                #pragma unroll
                for (int r = 0; r < 4; ++r)
                    en[i2 * 4 + r] = *reinterpret_cast<const float*>(
                        lds + 32768 + (cbl + wn * 64 + i2 * 16 + lg * 4 + r) * 4);
            #pragma unroll
            for (int j = 0; j < 4; ++j) {
                float v1[8], v2[8]; int g1[8], g2[8];
                #pragma unroll
                for (int k = 0; k < 8; ++k) {
                    int a = 2 * k, c = 2 * k + 1;
                    float da = fmaf(-2.f, acc[a >> 2][j][a & 3], en[a]);
                    float dc = fmaf(-2.f, acc[c >> 2][j][c & 3], en[c]);
                    bool w = dc < da;                 // strict: tie -> smaller slot
                    v1[k] = w ? dc : da; g1[k] = w ? c : a;
                    v2[k] = w ? da : dc; g2[k] = w ? a : c;
                }
                #pragma unroll
                for (int st = 4; st >= 1; st >>= 1)
                    #pragma unroll
                    for (int m = 0; m < st; ++m) {
                        float b1 = v1[m + st], b2 = v2[m + st];
                        int  b1s = g1[m + st], b2s = g2[m + st];
                        bool c1 = b1 < v1[m];
                        float hv = c1 ? v1[m] : b1;  int hs = c1 ? g1[m] : b1s;
                        v1[m] = c1 ? b1 : v1[m];     g1[m] = c1 ? b1s : g1[m];
                        bool c2 = b2 < v2[m];
                        float mv = c2 ? b2 : v2[m];  int ms = c2 ? b2s : g2[m];
                        bool c3 = mv < hv;
                        v2[m] = c3 ? mv : hv;        g2[m] = c3 ? ms : hs;
                    }
                int s1 = g1[0], s2 = g2[0];
                u32 code1 = (u32)(cb + wn * 64 + ((s1 >> 2) << 4) + lg * 4 + (s1 & 3));
                u32 code2 = (u32)(cb + wn * 64 + ((s2 >> 2) << 4) + lg * 4 + (s2 & 3));
                u64 k1 = ((u64)f2ord(v1[0]) << 32) | code1;
                u64 k2 = ((u64)f2ord(v2[0]) << 32) | code2;
                u64 n1 = k1 < t1[j] ? k1 : t1[j];
                u64 hi = k1 < t1[j] ? t1[j] : k1;
                u64 m2 = k2 < t2[j] ? k2 : t2[j];
                t1[j] = n1;
                t2[j] = hi < m2 ? hi : m2;
            }
            #pragma unroll
            for (int i2 = 0; i2 < 4; ++i2)
                #pragma unroll
                for (int j = 0; j < 4; ++j)
                    acc[i2][j] = (f4v){0.f, 0.f, 0.f, 0.f};
        }

        __syncthreads();                    // drains e-prefetch(sp+2) + zA loads
    }

    // cross-lane (lg) top-2 merge: lanes sharing (j, lr) hold same z-row
    #pragma unroll
    for (int j = 0; j < 4; ++j) {
        u64 a1 = t1[j], a2 = t2[j];
        #pragma unroll
        for (int mk = 16; mk <= 32; mk <<= 1) {
            u64 o1 = __shfl_xor(a1, mk);
            u64 o2 = __shfl_xor(a2, mk);
            u64 n1 = a1 < o1 ? a1 : o1;
            u64 hi = a1 < o1 ? o1 : a1;
            u64 m2 = a2 < o2 ? a2 : o2;
            a1 = n1;
            a2 = hi < m2 ? hi : m2;
        }
        t1[j] = a1; t2[j] = a2;
    }

    // cross-wave (wn) merge via LDS, then write cand[row][ch][2]
    __syncthreads();
    u64* mbuf = (u64*)lds;                   // 2KB reuse
    if (wn == 1 && lg == 0) {
        #pragma unroll
        for (int j = 0; j < 4; ++j) {
            int s = ((wm * 4 + j) * 16 + lr) * 2;
            mbuf[s] = t1[j]; mbuf[s + 1] = t2[j];
        }
    }
    __syncthreads();
    if (wn == 0 && lg == 0) {
        #pragma unroll
        for (int j = 0; j < 4; ++j) {
            int s = ((wm * 4 + j) * 16 + lr) * 2;
            u64 b1 = mbuf[s], b2 = mbuf[s + 1];
            u64 n1 = t1[j] < b1 ? t1[j] : b1;
            u64 hi = t1[j] < b1 ? b1 : t1[j];
            u64 m2 = t2[j] < b2 ? t2[j] : b2;
            u64 n2 = hi < m2 ? hi : m2;
            int row = r0 + wm * 64 + j * 16 + lr;
            cand[((size_t)row * NCHUNK + ch) * 2]     = n1;
            cand[((size_t)row * NCHUNK + ch) * 2 + 1] = n2;
        }
    }
}

// ---------------- exact fp32 rescore of 16 candidates + outputs ----------------
__global__ __launch_bounds__(256) void rescore_kernel(const float* __restrict__ z,
                                                      const float* __restrict__ emb,
                                                      const float* __restrict__ enorm,
                                                      const u64* __restrict__ cand,
                                                      float* __restrict__ out,
                                                      float* __restrict__ partials) {
    int row  = blockIdx.x * 4 + (threadIdx.x >> 6);
    int lane = threadIdx.x & 63;
    float4 zv = reinterpret_cast<const float4*>(z)[(size_t)row * 64 + lane];

    u64 best = ~0ULL;
    for (int s = 0; s < 2 * NCHUNK; ++s) {
        u32 c = ((u32)cand[(size_t)row * (2 * NCHUNK) + s]) & (K_CODES - 1);
        float4 ev = reinterpret_cast<const float4*>(emb)[(size_t)c * 64 + lane];
        float p = zv.x * ev.x + zv.y * ev.y + zv.z * ev.z + zv.w * ev.w;
        #pragma unroll
        for (int mk = 1; mk < 64; mk <<= 1) p += __shfl_xor(p, mk);
        float dist = fmaf(-2.f, p, enorm[c]);
        u64 key = ((u64)f2ord(dist) << 32) | c;
        best = key < best ? key : best;
    }
    u32 idx = ((u32)best) & (K_CODES - 1);
    if (lane == 0) out[IDX_OFF + row] = (float)idx;

    float4 ev = reinterpret_cast<const float4*>(emb)[(size_t)idx * 64 + lane];
    float tx = ev.x - zv.x, ty = ev.y - zv.y, tz = ev.z - zv.z, tw = ev.w - zv.w;
    float4 o;
    o.x = zv.x + tx; o.y = zv.y + ty; o.z = zv.z + tz; o.w = zv.w + tw;  // straight-through
    reinterpret_cast<float4*>(out)[(size_t)row * 64 + lane] = o;

    float s = tx * tx + ty * ty + tz * tz + tw * tw;
    #pragma unroll
    for (int off = 32; off >= 1; off >>= 1) s += __shfl_down(s, off);

    __shared__ float wsum[4];
    if (lane == 0) wsum[threadIdx.x >> 6] = s;
    __syncthreads();
    if (threadIdx.x == 0)
        partials[blockIdx.x] = (wsum[0] + wsum[1]) + (wsum[2] + wsum[3]);
}

__global__ __launch_bounds__(256) void loss_kernel(const float* __restrict__ partials,
                                                   float* __restrict__ out) {
    __shared__ float sm[256];
    float s = 0.0f;
    for (int i = threadIdx.x; i < 4096; i += 256) s += partials[i];
    sm[threadIdx.x] = s;
    __syncthreads();
    #pragma unroll
    for (int st = 128; st >= 1; st >>= 1) {
        if (threadIdx.x < st) sm[threadIdx.x] += sm[threadIdx.x + st];
        __syncthreads();
    }
    if (threadIdx.x == 0)
        out[LOSS_OFF] = sm[0] * (0.25f / (float)(N_ROWS * D_DIM));
}

extern "C" void kernel_launch(void* const* d_in, const int* in_sizes, int n_in,
                              void* d_out, int out_size, void* d_ws, size_t ws_size,
                              hipStream_t stream) {
    const float* z   = (const float*)d_in[0];
    const float* emb = (const float*)d_in[1];
    float* out = (float*)d_out;

    u64*   cand     = (u64*)d_ws;
    float* enorm    = (float*)((char*)d_ws + WS_ENORM_OFF);
    float* partials = (float*)((char*)d_ws + WS_PARTIAL_OFF);
    unsigned short* zh = (unsigned short*)((char*)d_ws + WS_ZH_OFF);
    unsigned short* zl = (unsigned short*)((char*)d_ws + WS_ZL_OFF);
    unsigned short* eh = (unsigned short*)((char*)d_ws + WS_EH_OFF);
    unsigned short* el = (unsigned short*)((char*)d_ws + WS_EL_OFF);

    zconv_kernel<<<4096, 256, 0, stream>>>(z, zh, zl);
    econv_kernel<<<2048, 256, 0, stream>>>(emb, eh, el, enorm);
    argmin_kernel<<<1024, 256, 0, stream>>>(zh, zl, eh, el, enorm, cand);
    rescore_kernel<<<N_ROWS / 4, 256, 0, stream>>>(z, emb, enorm, cand, out, partials);
    loss_kernel<<<1, 256, 0, stream>>>(partials, out);
}

// Round 20
// 144.795 us; speedup vs baseline: 2.6406x; 1.6096x over previous
//
#include <hip/hip_runtime.h>
#include <math.h>

#define D_DIM   256
#define N_ROWS  16384
#define K_CODES 8192
#define NCHUNK  8          // 8 chunks of 1024 codes

typedef __attribute__((ext_vector_type(8))) _Float16 h8v;        // 8 f16 (A/B frag)
typedef __attribute__((ext_vector_type(4))) float f4v;           // 4 f32  (C/D frag)
typedef __attribute__((ext_vector_type(4))) unsigned short us4;  // 4 f16 (8B write)
typedef unsigned long long u64;
typedef unsigned int u32;

// out layout: [0, 4194304) z_q_st | [4194304, 4210688) indices (as float) | [4210688] vq_loss
#define IDX_OFF  ((size_t)N_ROWS * D_DIM)
#define LOSS_OFF (IDX_OFF + N_ROWS)

// ws layout (15 MB used):
//   [0, 2MB)        u64 cand[N_ROWS][NCHUNK][2]
//   [2MB, +32KB)    float enorm[8192]
//   [+32KB, +16KB)  float partials[4096]
//   [3MB, 11MB)     f16 zh_t  K-major: [d0b][lg][row][16B]  (d0b<8, lg<4)
//   [11MB, 15MB)    f16 eh_t  [d0b][lg][code][16B]
#define WS_ENORM_OFF    (2u * 1024u * 1024u)
#define WS_PARTIAL_OFF  (WS_ENORM_OFF + 32768u)
#define WS_ZH_OFF       (3u * 1024u * 1024u)
#define WS_EH_OFF       (11u * 1024u * 1024u)

__device__ __forceinline__ unsigned short f2h(float f) {    // fp32 -> fp16 RNE
    _Float16 h = (_Float16)f;
    unsigned short u;
    __builtin_memcpy(&u, &h, 2);
    return u;
}
__device__ __forceinline__ u32 f2ord(float f) {             // monotonic fp32 -> u32
    u32 u = __float_as_uint(f);
    return (u & 0x80000000u) ? ~u : (u | 0x80000000u);
}
__device__ __forceinline__ void gl2lds16(const void* g, void* l) {
    __builtin_amdgcn_global_load_lds(
        (const __attribute__((address_space(1))) unsigned int*)g,
        (__attribute__((address_space(3))) unsigned int*)l, 16, 0, 0);
}

// ---- pre-convert: z -> zh_t fp16 (K-major tiling) ----
__global__ __launch_bounds__(256) void zconv_kernel(const float* __restrict__ z,
                                                    unsigned short* __restrict__ zh) {
    int q = blockIdx.x * 256 + threadIdx.x;        // float4 index, 0..1048575
    float4 v = reinterpret_cast<const float4*>(z)[q];
    us4 h;
    h[0] = f2h(v.x); h[1] = f2h(v.y); h[2] = f2h(v.z); h[3] = f2h(v.w);
    int row = q >> 6;                               // 64 float4 per row
    int f   = q & 63;                               // d = f*4 .. f*4+3
    int d0b = f >> 3, lg = (f >> 1) & 3, half = f & 1;
    size_t off = ((size_t)(d0b * 4 + lg) * N_ROWS + row) * 16 + half * 8;
    *reinterpret_cast<us4*>((char*)zh + off) = h;
}

// ---- pre-convert: emb -> eh_t fp16 (K-major tiling) + enorm (fused) ----
__global__ __launch_bounds__(256) void econv_kernel(const float* __restrict__ emb,
                                                    unsigned short* __restrict__ eh,
                                                    float* __restrict__ enorm) {
    int q = blockIdx.x * 256 + threadIdx.x;        // 0..524287
    float4 v = reinterpret_cast<const float4*>(emb)[q];

    // one wave == one codebook row (64 lanes x 4 floats): fused enorm
    float s = v.x * v.x + v.y * v.y + v.z * v.z + v.w * v.w;
    #pragma unroll
    for (int off = 32; off >= 1; off >>= 1) s += __shfl_down(s, off);

    us4 h;
    h[0] = f2h(v.x); h[1] = f2h(v.y); h[2] = f2h(v.z); h[3] = f2h(v.w);
    int row = q >> 6;
    int f   = q & 63;
    if (f == 0) enorm[row] = s;
    int d0b = f >> 3, lg = (f >> 1) & 3, half = f & 1;
    size_t off = ((size_t)(d0b * 4 + lg) * K_CODES + row) * 16 + half * 8;
    *reinterpret_cast<us4*>((char*)eh + off) = h;
}

// ---------------- MFMA argmin: fp16 single-pass screen ----------------
// ROUND-19/20 CHANGE: 3-pass bf16 split screen -> 1-pass fp16 screen
// (mfma_f32_16x16x32_f16; dist err ~2.4e-4 rms, crowding P ~1e-9/row ->
// top-2 + exact rescore unchanged-safe). 3x less MFMA, half staging bytes,
// steps refolded 64 -> 32 (2 d0b per step, half the barriers).
// Keeps: XCD 16x8 rectangle mapping (FETCH 523->41MB, round 18), e-only LDS
// staging, z-in-registers one step ahead, tournament epilogue, LDS enorm.
__global__ __launch_bounds__(256, 2) void argmin_kernel(const unsigned short* __restrict__ zh,
                                                        const unsigned short* __restrict__ eh,
                                                        const float* __restrict__ enorm,
                                                        u64* __restrict__ cand) {
    __shared__ __align__(16) unsigned char lds[36864];   // 2x16KB e-dbuf + 4KB enorm

    const int tid = threadIdx.x;
    const int wv  = tid >> 6;
    const int l   = tid & 63;
    const int lr  = l & 15;
    const int lg  = l >> 4;
    const int wm  = wv >> 1;                // row half: rows wm*64..+63
    const int wn  = wv & 1;                 // code half: codes wn*64..+63
    const int wg  = blockIdx.x;
    const int x   = wg & 7;                 // XCD (round-robin dispatch)
    const int i   = wg >> 3;                // 0..127 within XCD
    const int ch  = i >> 4;                 // chunk 0..7
    const int r0    = x * 2048 + (i & 15) * 128;   // row-block in XCD's 2048-row slice
    const int cbase = ch * 1024;

    const char* zhp = (const char*)zh;
    const char* ehp = (const char*)eh;

    // enorm slice -> LDS via normal load + ds_write (no vmcnt-queue pollution)
    {
        float4 ev = *reinterpret_cast<const float4*>(enorm + cbase + tid * 4);
        *reinterpret_cast<float4*>(lds + 32768 + tid * 16) = ev;
    }

    // e-stage per-thread source bases; per-step offsets: d0b<<19, ct<<11
    const int tsw = tid >> 7, tix = tid & 127;
    const size_t E0a = ((size_t)tsw       * K_CODES + cbase + tix) * 16;
    const size_t E0b = ((size_t)(tsw + 2) * K_CODES + cbase + tix) * 16;

    // step s (0..31): ct = s>>2, d0b pair = {(s&3)*2, (s&3)*2+1}
    auto stage = [&](int s, int b) {
        char* dst = (char*)lds + b * 16384 + tid * 16;
        const size_t u0 = (((size_t)((s & 3) * 2)) << 19) + (((size_t)(s >> 2)) << 11);
        const size_t u1 = u0 + (1u << 19);
        gl2lds16(ehp + E0a + u0, dst);
        gl2lds16(ehp + E0b + u0, dst + 4096);
        gl2lds16(ehp + E0a + u1, dst + 8192);
        gl2lds16(ehp + E0b + u1, dst + 12288);
    };

    // z-frag per-thread byte bases (d0b stride = 1MB = 1<<20)
    size_t Zb[4];
    #pragma unroll
    for (int j = 0; j < 4; ++j)
        Zb[j] = ((size_t)lg * N_ROWS + r0 + wm * 64 + j * 16 + lr) * 16;

    u64 t1[4], t2[4];                       // top-2 per owned row-tile j
    #pragma unroll
    for (int j = 0; j < 4; ++j) { t1[j] = ~0ULL; t2[j] = ~0ULL; }

    f4v acc[4][4];
    #pragma unroll
    for (int i2 = 0; i2 < 4; ++i2)
        #pragma unroll
        for (int j = 0; j < 4; ++j)
            acc[i2][j] = (f4v){0.f, 0.f, 0.f, 0.f};

    h8v zA[2][4], zB[2][4];                 // [d0b-half][j], named sets (rule #20)
    // prologue: zA for step 0 (d0b 0,1); e-stage step 0
    #pragma unroll
    for (int h = 0; h < 2; ++h)
        #pragma unroll
        for (int j = 0; j < 4; ++j)
            zA[h][j] = *reinterpret_cast<const h8v*>(zhp + Zb[j] + ((size_t)h << 20));
    stage(0, 0);
    __syncthreads();                        // buf0 + enorm ready

    for (int sp = 0; sp < 32; sp += 2) {
        // ---- step sp (even): e-buf 0, compute with zA; prefetch step sp+1 ----
        stage(sp + 1, 1);
        {
            const int dd = ((sp + 1) & 3) * 2;
            #pragma unroll
            for (int h = 0; h < 2; ++h)
                #pragma unroll
                for (int j = 0; j < 4; ++j)
                    zB[h][j] = *reinterpret_cast<const h8v*>(
                        zhp + Zb[j] + ((size_t)(dd + h) << 20));
        }
        {
            const char* base = (const char*)lds;             // buf 0
            #pragma unroll
            for (int h = 0; h < 2; ++h)
                #pragma unroll
                for (int i2 = 0; i2 < 4; ++i2) {
                    int code = wn * 64 + i2 * 16 + lr;
                    h8v ehf = *reinterpret_cast<const h8v*>(
                        base + h * 8192 + lg * 2048 + code * 16);
                    #pragma unroll
                    for (int j = 0; j < 4; ++j)
                        acc[i2][j] = __builtin_amdgcn_mfma_f32_16x16x32_f16(
                            ehf, zA[h][j], acc[i2][j], 0, 0, 0);
                }
        }
        __syncthreads();                    // drains e-prefetch(sp+1) + zB loads

        // ---- step sp+1 (odd): e-buf 1, compute with zB; prefetch step sp+2 ----
        if (sp + 2 < 32) {
            stage(sp + 2, 0);
            const int dd = ((sp + 2) & 3) * 2;
            #pragma unroll
            for (int h = 0; h < 2; ++h)
                #pragma unroll
                for (int j = 0; j < 4; ++j)
                    zA[h][j] = *reinterpret_cast<const h8v*>(
                        zhp + Zb[j] + ((size_t)(dd + h) << 20));
        }
        {
            const char* base = (const char*)lds + 16384;     // buf 1
            #pragma unroll
            for (int h = 0; h < 2; ++h)
                #pragma unroll
                for (int i2 = 0; i2 < 4; ++i2) {
                    int code = wn * 64 + i2 * 16 + lr;
                    h8v ehf = *reinterpret_cast<const h8v*>(
                        base + h * 8192 + lg * 2048 + code * 16);
                    #pragma unroll
                    for (int j = 0; j < 4; ++j)
                        acc[i2][j] = __builtin_amdgcn_mfma_f32_16x16x32_f16(
                            ehf, zB[h][j], acc[i2][j], 0, 0, 0);
                }
        }

        if (((sp + 1) & 3) == 3) {
            // epilogue for ct = (sp+1)>>2: dist = enorm - 2*dot (enorm from LDS),
            // fp32 (value,slot) tournament top-2 per row j, then u64 key merge.
            const int cbl = ((sp + 1) >> 2) * 128;
            const int cb  = cbase + cbl;
            float en[16];
            #pragma unroll
            for (int i2 = 0; i2 < 4; ++i2)
                #pragma unroll
                for (int r = 0; r < 4; ++r)
                    en[i2 * 4 + r] = *reinterpret_cast<const float*>(
                        lds + 32768 + (cbl + wn * 64 + i2 * 16 + lg * 4 + r) * 4);
            #pragma unroll
            for (int j = 0; j < 4; ++j) {
                float v1[8], v2[8]; int g1[8], g2[8];
                #pragma unroll
                for (int k = 0; k < 8; ++k) {
                    int a = 2 * k, c = 2 * k + 1;
                    float da = fmaf(-2.f, acc[a >> 2][j][a & 3], en[a]);
                    float dc = fmaf(-2.f, acc[c >> 2][j][c & 3], en[c]);
                    bool w = dc < da;                 // strict: tie -> smaller slot
                    v1[k] = w ? dc : da; g1[k] = w ? c : a;
                    v2[k] = w ? da : dc; g2[k] = w ? a : c;
                }
                #pragma unroll
                for (int st = 4; st >= 1; st >>= 1)
                    #pragma unroll
                    for (int m = 0; m < st; ++m) {
                        float b1 = v1[m + st], b2 = v2[m + st];
                        int  b1s = g1[m + st], b2s = g2[m + st];
                        bool c1 = b1 < v1[m];
                        float hv = c1 ? v1[m] : b1;  int hs = c1 ? g1[m] : b1s;
                        v1[m] = c1 ? b1 : v1[m];     g1[m] = c1 ? b1s : g1[m];
                        bool c2 = b2 < v2[m];
                        float mv = c2 ? b2 : v2[m];  int ms = c2 ? b2s : g2[m];
                        bool c3 = mv < hv;
                        v2[m] = c3 ? mv : hv;        g2[m] = c3 ? ms : hs;
                    }
                int s1 = g1[0], s2 = g2[0];
                u32 code1 = (u32)(cb + wn * 64 + ((s1 >> 2) << 4) + lg * 4 + (s1 & 3));
                u32 code2 = (u32)(cb + wn * 64 + ((s2 >> 2) << 4) + lg * 4 + (s2 & 3));
                u64 k1 = ((u64)f2ord(v1[0]) << 32) | code1;
                u64 k2 = ((u64)f2ord(v2[0]) << 32) | code2;
                u64 n1 = k1 < t1[j] ? k1 : t1[j];
                u64 hi = k1 < t1[j] ? t1[j] : k1;
                u64 m2 = k2 < t2[j] ? k2 : t2[j];
                t1[j] = n1;
                t2[j] = hi < m2 ? hi : m2;
            }
            #pragma unroll
            for (int i2 = 0; i2 < 4; ++i2)
                #pragma unroll
                for (int j = 0; j < 4; ++j)
                    acc[i2][j] = (f4v){0.f, 0.f, 0.f, 0.f};
        }

        __syncthreads();                    // drains e-prefetch(sp+2) + zA loads
    }

    // cross-lane (lg) top-2 merge: lanes sharing (j, lr) hold same z-row
    #pragma unroll
    for (int j = 0; j < 4; ++j) {
        u64 a1 = t1[j], a2 = t2[j];
        #pragma unroll
        for (int mk = 16; mk <= 32; mk <<= 1) {
            u64 o1 = __shfl_xor(a1, mk);
            u64 o2 = __shfl_xor(a2, mk);
            u64 n1 = a1 < o1 ? a1 : o1;
            u64 hi = a1 < o1 ? o1 : a1;
            u64 m2 = a2 < o2 ? a2 : o2;
            a1 = n1;
            a2 = hi < m2 ? hi : m2;
        }
        t1[j] = a1; t2[j] = a2;
    }

    // cross-wave (wn) merge via LDS, then write cand[row][ch][2]
    __syncthreads();
    u64* mbuf = (u64*)lds;                   // 2KB reuse
    if (wn == 1 && lg == 0) {
        #pragma unroll
        for (int j = 0; j < 4; ++j) {
            int s = ((wm * 4 + j) * 16 + lr) * 2;
            mbuf[s] = t1[j]; mbuf[s + 1] = t2[j];
        }
    }
    __syncthreads();
    if (wn == 0 && lg == 0) {
        #pragma unroll
        for (int j = 0; j < 4; ++j) {
            int s = ((wm * 4 + j) * 16 + lr) * 2;
            u64 b1 = mbuf[s], b2 = mbuf[s + 1];
            u64 n1 = t1[j] < b1 ? t1[j] : b1;
            u64 hi = t1[j] < b1 ? b1 : t1[j];
            u64 m2 = t2[j] < b2 ? t2[j] : b2;
            u64 n2 = hi < m2 ? hi : m2;
            int row = r0 + wm * 64 + j * 16 + lr;
            cand[((size_t)row * NCHUNK + ch) * 2]     = n1;
            cand[((size_t)row * NCHUNK + ch) * 2 + 1] = n2;
        }
    }
}

// ---------------- exact fp32 rescore of 16 candidates + outputs ----------------
__global__ __launch_bounds__(256) void rescore_kernel(const float* __restrict__ z,
                                                      const float* __restrict__ emb,
                                                      const float* __restrict__ enorm,
                                                      const u64* __restrict__ cand,
                                                      float* __restrict__ out,
                                                      float* __restrict__ partials) {
    int row  = blockIdx.x * 4 + (threadIdx.x >> 6);
    int lane = threadIdx.x & 63;
    float4 zv = reinterpret_cast<const float4*>(z)[(size_t)row * 64 + lane];

    u64 best = ~0ULL;
    for (int s = 0; s < 2 * NCHUNK; ++s) {
        u32 c = ((u32)cand[(size_t)row * (2 * NCHUNK) + s]) & (K_CODES - 1);
        float4 ev = reinterpret_cast<const float4*>(emb)[(size_t)c * 64 + lane];
        float p = zv.x * ev.x + zv.y * ev.y + zv.z * ev.z + zv.w * ev.w;
        #pragma unroll
        for (int mk = 1; mk < 64; mk <<= 1) p += __shfl_xor(p, mk);
        float dist = fmaf(-2.f, p, enorm[c]);
        u64 key = ((u64)f2ord(dist) << 32) | c;
        best = key < best ? key : best;
    }
    u32 idx = ((u32)best) & (K_CODES - 1);
    if (lane == 0) out[IDX_OFF + row] = (float)idx;

    float4 ev = reinterpret_cast<const float4*>(emb)[(size_t)idx * 64 + lane];
    float tx = ev.x - zv.x, ty = ev.y - zv.y, tz = ev.z - zv.z, tw = ev.w - zv.w;
    float4 o;
    o.x = zv.x + tx; o.y = zv.y + ty; o.z = zv.z + tz; o.w = zv.w + tw;  // straight-through
    reinterpret_cast<float4*>(out)[(size_t)row * 64 + lane] = o;

    float s = tx * tx + ty * ty + tz * tz + tw * tw;
    #pragma unroll
    for (int off = 32; off >= 1; off >>= 1) s += __shfl_down(s, off);

    __shared__ float wsum[4];
    if (lane == 0) wsum[threadIdx.x >> 6] = s;
    __syncthreads();
    if (threadIdx.x == 0)
        partials[blockIdx.x] = (wsum[0] + wsum[1]) + (wsum[2] + wsum[3]);
}

__global__ __launch_bounds__(256) void loss_kernel(const float* __restrict__ partials,
                                                   float* __restrict__ out) {
    __shared__ float sm[256];
    float s = 0.0f;
    for (int i = threadIdx.x; i < 4096; i += 256) s += partials[i];
    sm[threadIdx.x] = s;
    __syncthreads();
    #pragma unroll
    for (int st = 128; st >= 1; st >>= 1) {
        if (threadIdx.x < st) sm[threadIdx.x] += sm[threadIdx.x + st];
        __syncthreads();
    }
    if (threadIdx.x == 0)
        out[LOSS_OFF] = sm[0] * (0.25f / (float)(N_ROWS * D_DIM));
}

extern "C" void kernel_launch(void* const* d_in, const int* in_sizes, int n_in,
                              void* d_out, int out_size, void* d_ws, size_t ws_size,
                              hipStream_t stream) {
    const float* z   = (const float*)d_in[0];
    const float* emb = (const float*)d_in[1];
    float* out = (float*)d_out;

    u64*   cand     = (u64*)d_ws;
    float* enorm    = (float*)((char*)d_ws + WS_ENORM_OFF);
    float* partials = (float*)((char*)d_ws + WS_PARTIAL_OFF);
    unsigned short* zh = (unsigned short*)((char*)d_ws + WS_ZH_OFF);
    unsigned short* eh = (unsigned short*)((char*)d_ws + WS_EH_OFF);

    zconv_kernel<<<4096, 256, 0, stream>>>(z, zh);
    econv_kernel<<<2048, 256, 0, stream>>>(emb, eh, enorm);
    argmin_kernel<<<1024, 256, 0, stream>>>(zh, eh, enorm, cand);
    rescore_kernel<<<N_ROWS / 4, 256, 0, stream>>>(z, emb, enorm, cand, out, partials);
    loss_kernel<<<1, 256, 0, stream>>>(partials, out);
}